// Round 3
// baseline (211.972 us; speedup 1.0000x reference)
//
#include <hip/hip_runtime.h>

typedef __attribute__((ext_vector_type(8))) short bf16x8;
typedef __attribute__((ext_vector_type(4))) short bf16x4;
typedef __attribute__((ext_vector_type(4))) float f32x4;

#define NB 128
#define LL 512
#define HH 128
#define HDIM 64
#define NROWS (NB * LL)  // 65536

__device__ __forceinline__ unsigned short f2b(float f) {
  unsigned int x = __float_as_uint(f);
  x = (x + 0x7fffu + ((x >> 16) & 1u)) >> 16;  // RNE
  return (unsigned short)x;
}

__device__ __forceinline__ bf16x8 load8_cvt(const float* p) {
  float4 a = *(const float4*)p;
  float4 b = *(const float4*)(p + 4);
  bf16x8 r;
  r[0] = (short)f2b(a.x); r[1] = (short)f2b(a.y);
  r[2] = (short)f2b(a.z); r[3] = (short)f2b(a.w);
  r[4] = (short)f2b(b.x); r[5] = (short)f2b(b.y);
  r[6] = (short)f2b(b.z); r[7] = (short)f2b(b.w);
  return r;
}

#if __has_builtin(__builtin_amdgcn_mfma_f32_16x16x16bf16_1k)
__device__ __forceinline__ f32x4 mfma16(bf16x4 a, bf16x4 b, f32x4 c) {
  return __builtin_amdgcn_mfma_f32_16x16x16bf16_1k(a, b, c, 0, 0, 0);
}
#else
__device__ __forceinline__ f32x4 mfma16(bf16x4 a, bf16x4 b, f32x4 c) {
  asm volatile("s_nop 1\n\t"
               "v_mfma_f32_16x16x16_bf16 %0, %1, %2, %0\n\t"
               "s_nop 7\n\t"
               "s_nop 7"
               : "+v"(c) : "v"(a), "v"(b));
  return c;
}
#endif

__device__ __forceinline__ f32x4 mfma32(bf16x8 a, bf16x8 b, f32x4 c) {
  return __builtin_amdgcn_mfma_f32_16x16x32_bf16(a, b, c, 0, 0, 0);
}

// ---------------------------------------------------------------------------
// Weight pre-convert: Qw,Kw,Vw fp32 -> bf16, row-major [3][128][128].
// 12288 threads x 4 floats.
// ---------------------------------------------------------------------------
__global__ __launch_bounds__(256) void wcvt_kernel(
    const float* __restrict__ Qw, const float* __restrict__ Kw,
    const float* __restrict__ Vw, unsigned short* __restrict__ Wb) {
  const int i = blockIdx.x * 256 + threadIdx.x;  // 0..12287
  const float* src = (i < 4096) ? Qw : (i < 8192) ? Kw : Vw;
  const int off = (i & 4095) << 2;
  float4 v = *(const float4*)(src + off);
  ushort4 u;
  u.x = f2b(v.x); u.y = f2b(v.y); u.z = f2b(v.z); u.w = f2b(v.w);
  *(ushort4*)(Wb + ((size_t)i << 2)) = u;
}

// ---------------------------------------------------------------------------
// Projection kernel v3: no LDS, no barriers. Swapped MFMA operands
// (A = W rows, B = X rows) so each lane's C fragment = its OWN row x 4
// consecutive cols -> float4 epilogue loads, ushort4 stores.
//   Ko [65536][128] = keys @ Kw^T + Kb + nbr + nat + pk   (bf16)
//   Vt [2][128][64][512]  = (keys @ Vw^T + Vb + nbr + nat + pv)^T
//   Qo [65536][128] = queries @ Qw^T + Qb
// Grid: 1024 blocks x 256 threads; wave = 16 rows, block = 64 rows.
// ---------------------------------------------------------------------------
__global__ __launch_bounds__(256) void proj_kernel(
    const float* __restrict__ queries, const float* __restrict__ keys,
    const float* __restrict__ nbr, const float* __restrict__ nat,
    const float* __restrict__ pk, const float* __restrict__ pv,
    const unsigned short* __restrict__ Wb,
    const float* __restrict__ Qbias, const float* __restrict__ Kbias,
    const float* __restrict__ Vbias,
    unsigned short* __restrict__ Qo, unsigned short* __restrict__ Ko,
    unsigned short* __restrict__ Vt) {
  const int tid = threadIdx.x;
  const int lane = tid & 63;
  const int wave = tid >> 6;
  const int g = lane >> 4;    // 0..3
  const int qi = lane & 15;   // 0..15
  const long row = (long)blockIdx.x * 64 + wave * 16 + qi;  // lane's output row

  // X fragment (B operand): lane = col j = its own row; k = kt*32 + g*8 + j
  bf16x8 xk[4];
#pragma unroll
  for (int kt = 0; kt < 4; ++kt)
    xk[kt] = load8_cvt(keys + row * 128 + kt * 32 + g * 8);

  f32x4 acc[8];
  float4 tmp[8];  // nbr+nat, carried from K epilogue to V epilogue

  // ---------------- K projection ----------------
#pragma unroll
  for (int ct = 0; ct < 8; ++ct) {
    acc[ct] = f32x4{0.f, 0.f, 0.f, 0.f};
#pragma unroll
    for (int kt = 0; kt < 4; ++kt) {
      // A fragment: W row = out col ct*16+qi, k = kt*32 + g*8 + j
      bf16x8 wf = *(const bf16x8*)(Wb + 16384 + (ct * 16 + qi) * 128 + kt * 32 + g * 8);
      acc[ct] = mfma32(wf, xk[kt], acc[ct]);
    }
  }
  // C layout after swap: lane holds out[row][c0..c0+3], c0 = ct*16 + 4g
#pragma unroll
  for (int ct = 0; ct < 8; ++ct) {
    const int c0 = ct * 16 + 4 * g;
    const float4 bv = *(const float4*)(Kbias + c0);
    const float4 nb = *(const float4*)(nbr + row * 128 + c0);
    const float4 na = *(const float4*)(nat + row * 128 + c0);
    const float4 p4 = *(const float4*)(pk + row * 128 + c0);
    float4 t;
    t.x = nb.x + na.x; t.y = nb.y + na.y; t.z = nb.z + na.z; t.w = nb.w + na.w;
    tmp[ct] = t;
    ushort4 u;
    u.x = f2b(acc[ct][0] + bv.x + t.x + p4.x);
    u.y = f2b(acc[ct][1] + bv.y + t.y + p4.y);
    u.z = f2b(acc[ct][2] + bv.z + t.z + p4.z);
    u.w = f2b(acc[ct][3] + bv.w + t.w + p4.w);
    *(ushort4*)(Ko + row * 128 + c0) = u;
  }

  // ---------------- V projection ----------------
#pragma unroll
  for (int ct = 0; ct < 8; ++ct) {
    acc[ct] = f32x4{0.f, 0.f, 0.f, 0.f};
#pragma unroll
    for (int kt = 0; kt < 4; ++kt) {
      bf16x8 wf = *(const bf16x8*)(Wb + 32768 + (ct * 16 + qi) * 128 + kt * 32 + g * 8);
      acc[ct] = mfma32(wf, xk[kt], acc[ct]);
    }
  }
  {
    const long bidx = row >> 9, lrow = row & 511;
#pragma unroll
    for (int ct = 0; ct < 8; ++ct) {
      const int c0 = ct * 16 + 4 * g;
      const float4 bv = *(const float4*)(Vbias + c0);
      const float4 p4 = *(const float4*)(pv + row * 128 + c0);
      const int hh = c0 >> 6, d0 = c0 & 63;
      unsigned short* vp = Vt + (((long)hh * NB + bidx) * HDIM + d0) * LL + lrow;
      vp[0 * LL] = f2b(acc[ct][0] + bv.x + tmp[ct].x + p4.x);
      vp[1 * LL] = f2b(acc[ct][1] + bv.y + tmp[ct].y + p4.y);
      vp[2 * LL] = f2b(acc[ct][2] + bv.z + tmp[ct].z + p4.z);
      vp[3 * LL] = f2b(acc[ct][3] + bv.w + tmp[ct].w + p4.w);
    }
  }

  // ---------------- Q projection ----------------
  bf16x8 xq[4];
#pragma unroll
  for (int kt = 0; kt < 4; ++kt)
    xq[kt] = load8_cvt(queries + row * 128 + kt * 32 + g * 8);
#pragma unroll
  for (int ct = 0; ct < 8; ++ct) {
    acc[ct] = f32x4{0.f, 0.f, 0.f, 0.f};
#pragma unroll
    for (int kt = 0; kt < 4; ++kt) {
      bf16x8 wf = *(const bf16x8*)(Wb + (ct * 16 + qi) * 128 + kt * 32 + g * 8);
      acc[ct] = mfma32(wf, xq[kt], acc[ct]);
    }
  }
#pragma unroll
  for (int ct = 0; ct < 8; ++ct) {
    const int c0 = ct * 16 + 4 * g;
    const float4 bv = *(const float4*)(Qbias + c0);
    ushort4 u;
    u.x = f2b(acc[ct][0] + bv.x);
    u.y = f2b(acc[ct][1] + bv.y);
    u.z = f2b(acc[ct][2] + bv.z);
    u.w = f2b(acc[ct][3] + bv.w);
    *(ushort4*)(Qo + row * 128 + c0) = u;
  }
}

// ---------------------------------------------------------------------------
// Attention kernel (unchanged from R2): K-tile = 64 keys/iter, 32 q/wave.
// ---------------------------------------------------------------------------
__global__ __launch_bounds__(256) void attn_kernel(
    const unsigned short* __restrict__ Qb, const unsigned short* __restrict__ Kb,
    const unsigned short* __restrict__ Vt, float* __restrict__ out) {
  const int qt = blockIdx.x;
  const int b = blockIdx.y;
  const int h = blockIdx.z;
  const int tid = threadIdx.x;
  const int lane = tid & 63;
  const int wave = tid >> 6;
  const int g = lane >> 4;
  const int qi = lane & 15;
  const int qbase = qt * 128 + wave * 32;

  bf16x8 qf[2][2];
#pragma unroll
  for (int q2 = 0; q2 < 2; ++q2) {
    const unsigned short* Qrow =
        Qb + ((long)(b * LL + qbase + q2 * 16 + qi)) * HH + h * HDIM;
    qf[q2][0] = *(const bf16x8*)(Qrow + g * 8);
    qf[q2][1] = *(const bf16x8*)(Qrow + 32 + g * 8);
  }

  f32x4 o[2][4];
#pragma unroll
  for (int q2 = 0; q2 < 2; ++q2)
#pragma unroll
    for (int dt = 0; dt < 4; ++dt) o[q2][dt] = f32x4{0.f, 0.f, 0.f, 0.f};
  float m[2] = {-1e30f, -1e30f};
  float lsum[2] = {0.f, 0.f};

  const int ntile = (qbase >> 6) + 1;
  const unsigned short* Vbase = Vt + ((long)(h * NB + b)) * HDIM * LL;

  for (int it = 0; it < ntile; ++it) {
    const int k0 = it * 64;

    bf16x8 kf[4][2];
#pragma unroll
    for (int t = 0; t < 4; ++t) {
      const unsigned short* Krow =
          Kb + ((long)(b * LL + k0 + t * 16 + qi)) * HH + h * HDIM;
      kf[t][0] = *(const bf16x8*)(Krow + g * 8);
      kf[t][1] = *(const bf16x8*)(Krow + 32 + g * 8);
    }

    f32x4 s[2][4];
#pragma unroll
    for (int q2 = 0; q2 < 2; ++q2)
#pragma unroll
      for (int t = 0; t < 4; ++t) {
        f32x4 acc = f32x4{0.f, 0.f, 0.f, 0.f};
        acc = mfma32(kf[t][0], qf[q2][0], acc);
        acc = mfma32(kf[t][1], qf[q2][1], acc);
        s[q2][t] = acc;
      }

    float alpha[2];
    bf16x4 pf[2][4];
#pragma unroll
    for (int q2 = 0; q2 < 2; ++q2) {
      const int myq = qbase + q2 * 16 + qi;
      float p[16];
      float pm = -1e30f;
#pragma unroll
      for (int t = 0; t < 4; ++t)
#pragma unroll
        for (int r = 0; r < 4; ++r) {
          float sv = s[q2][t][r] * 0.125f;
          const int key = k0 + t * 16 + 4 * g + r;
          sv = (key > myq) ? -1e30f : sv;
          p[t * 4 + r] = sv;
          pm = fmaxf(pm, sv);
        }
      pm = fmaxf(pm, __shfl_xor(pm, 16));
      pm = fmaxf(pm, __shfl_xor(pm, 32));
      const float mnew = fmaxf(m[q2], pm);
      alpha[q2] = exp2f((m[q2] - mnew) * 1.44269504f);
      float ps = 0.f;
#pragma unroll
      for (int i = 0; i < 16; ++i) {
        p[i] = exp2f((p[i] - mnew) * 1.44269504f);
        ps += p[i];
      }
      ps += __shfl_xor(ps, 16);
      ps += __shfl_xor(ps, 32);
      lsum[q2] = lsum[q2] * alpha[q2] + ps;
      m[q2] = mnew;
#pragma unroll
      for (int t = 0; t < 4; ++t) {
        pf[q2][t][0] = (short)f2b(p[t * 4 + 0]);
        pf[q2][t][1] = (short)f2b(p[t * 4 + 1]);
        pf[q2][t][2] = (short)f2b(p[t * 4 + 2]);
        pf[q2][t][3] = (short)f2b(p[t * 4 + 3]);
      }
    }

    float ar[2][4];
#pragma unroll
    for (int q2 = 0; q2 < 2; ++q2)
#pragma unroll
      for (int r = 0; r < 4; ++r) ar[q2][r] = __shfl(alpha[q2], 4 * g + r);

#pragma unroll
    for (int dt = 0; dt < 4; ++dt) {
#pragma unroll
      for (int q2 = 0; q2 < 2; ++q2) {
        o[q2][dt][0] *= ar[q2][0];
        o[q2][dt][1] *= ar[q2][1];
        o[q2][dt][2] *= ar[q2][2];
        o[q2][dt][3] *= ar[q2][3];
      }
#pragma unroll
      for (int t = 0; t < 4; ++t) {
        const bf16x4 vf =
            *(const bf16x4*)(Vbase + (dt * 16 + qi) * LL + k0 + t * 16 + 4 * g);
        o[0][dt] = mfma16(pf[0][t], vf, o[0][dt]);
        o[1][dt] = mfma16(pf[1][t], vf, o[1][dt]);
      }
    }
  }

#pragma unroll
  for (int q2 = 0; q2 < 2; ++q2) {
    float linv[4];
#pragma unroll
    for (int r = 0; r < 4; ++r) linv[r] = 1.0f / __shfl(lsum[q2], 4 * g + r);
#pragma unroll
    for (int dt = 0; dt < 4; ++dt)
#pragma unroll
      for (int r = 0; r < 4; ++r) {
        const long row = (long)(b * LL + qbase + q2 * 16 + 4 * g + r);
        out[row * HH + h * HDIM + dt * 16 + qi] = o[q2][dt][r] * linv[r];
      }
  }
}

extern "C" void kernel_launch(void* const* d_in, const int* in_sizes, int n_in,
                              void* d_out, int out_size, void* d_ws, size_t ws_size,
                              hipStream_t stream) {
  const float* queries = (const float*)d_in[0];
  const float* keys    = (const float*)d_in[1];
  const float* nbr     = (const float*)d_in[2];
  const float* nat     = (const float*)d_in[3];
  const float* pk      = (const float*)d_in[4];
  const float* pv      = (const float*)d_in[5];
  const float* Qw      = (const float*)d_in[6];
  const float* Qbias   = (const float*)d_in[7];
  const float* Kw      = (const float*)d_in[8];
  const float* Kbias   = (const float*)d_in[9];
  const float* Vw      = (const float*)d_in[10];
  const float* Vbias   = (const float*)d_in[11];
  // d_in[12] = attn_mask: exact causal ~tril, computed analytically in-kernel.

  unsigned short* Qo = (unsigned short*)d_ws;
  unsigned short* Ko = Qo + (size_t)NROWS * HH;
  unsigned short* Vt = Ko + (size_t)NROWS * HH;
  unsigned short* Wb = Vt + (size_t)NROWS * HH;  // [3][128][128] bf16

  wcvt_kernel<<<48, 256, 0, stream>>>(Qw, Kw, Vw, Wb);

  proj_kernel<<<NROWS / 64, 256, 0, stream>>>(queries, keys, nbr, nat, pk, pv,
                                              Wb, Qbias, Kbias, Vbias,
                                              Qo, Ko, Vt);

  dim3 grid(LL / 128, NB, 2);
  attn_kernel<<<grid, 256, 0, stream>>>(Qo, Ko, Vt, (float*)d_out);
}

// Round 4
// 161.226 us; speedup vs baseline: 1.3147x; 1.3147x over previous
//
#include <hip/hip_runtime.h>

typedef __attribute__((ext_vector_type(8))) short bf16x8;
typedef __attribute__((ext_vector_type(4))) short bf16x4;
typedef __attribute__((ext_vector_type(4))) float f32x4;

#define NB 128
#define LL 512
#define HH 128
#define HDIM 64
#define NROWS (NB * LL)  // 65536

__device__ __forceinline__ unsigned short f2b(float f) {
  unsigned int x = __float_as_uint(f);
  x = (x + 0x7fffu + ((x >> 16) & 1u)) >> 16;  // RNE
  return (unsigned short)x;
}

__device__ __forceinline__ bf16x8 load8_cvt(const float* p) {
  float4 a = *(const float4*)p;
  float4 b = *(const float4*)(p + 4);
  bf16x8 r;
  r[0] = (short)f2b(a.x); r[1] = (short)f2b(a.y);
  r[2] = (short)f2b(a.z); r[3] = (short)f2b(a.w);
  r[4] = (short)f2b(b.x); r[5] = (short)f2b(b.y);
  r[6] = (short)f2b(b.z); r[7] = (short)f2b(b.w);
  return r;
}

#if __has_builtin(__builtin_amdgcn_mfma_f32_16x16x16bf16_1k)
__device__ __forceinline__ f32x4 mfma16(bf16x4 a, bf16x4 b, f32x4 c) {
  return __builtin_amdgcn_mfma_f32_16x16x16bf16_1k(a, b, c, 0, 0, 0);
}
#else
__device__ __forceinline__ f32x4 mfma16(bf16x4 a, bf16x4 b, f32x4 c) {
  asm volatile("s_nop 1\n\t"
               "v_mfma_f32_16x16x16_bf16 %0, %1, %2, %0\n\t"
               "s_nop 7\n\t"
               "s_nop 7"
               : "+v"(c) : "v"(a), "v"(b));
  return c;
}
#endif

__device__ __forceinline__ f32x4 mfma32(bf16x8 a, bf16x8 b, f32x4 c) {
  return __builtin_amdgcn_mfma_f32_16x16x32_bf16(a, b, c, 0, 0, 0);
}

// ---------------------------------------------------------------------------
// Weight pre-convert: fp32 -> bf16, LINEAR layout Wb[3][128][128] (Q,K,V).
// ---------------------------------------------------------------------------
__global__ __launch_bounds__(256) void wcvt_kernel(
    const float* __restrict__ Qw, const float* __restrict__ Kw,
    const float* __restrict__ Vw, unsigned short* __restrict__ Wb) {
  const int i = blockIdx.x * 256 + threadIdx.x;  // 0..12287 float4s
  const float* src = (i < 4096) ? Qw : (i < 8192) ? Kw : Vw;
  const int off = (i & 4095) << 2;
  float4 v = *(const float4*)(src + off);
  ushort4 u;
  u.x = f2b(v.x); u.y = f2b(v.y); u.z = f2b(v.z); u.w = f2b(v.w);
  *(ushort4*)(Wb + ((size_t)i << 2)) = u;
}

// ---------------------------------------------------------------------------
// Projection kernel v4: all 3 weight matrices staged ONCE into 96KB LDS
// (XOR-swizzled rows, one barrier), then 3 barrier-free streaming GEMMs with
// swapped MFMA operands (A = W rows from LDS, B = X rows in regs) so each
// lane's C fragment = its OWN row x 4 consecutive cols -> float4/ushort4
// epilogue.
// Grid: 256 blocks x 1024 threads (16 waves x 16 rows = 256 rows/block).
// ---------------------------------------------------------------------------
__global__ __launch_bounds__(1024) void proj_kernel(
    const float* __restrict__ queries, const float* __restrict__ keys,
    const float* __restrict__ nbr, const float* __restrict__ nat,
    const float* __restrict__ pk, const float* __restrict__ pv,
    const unsigned short* __restrict__ Wb,
    const float* __restrict__ Qbias, const float* __restrict__ Kbias,
    const float* __restrict__ Vbias,
    unsigned short* __restrict__ Qo, unsigned short* __restrict__ Ko,
    unsigned short* __restrict__ Vt) {
  __shared__ unsigned short wlds[3 * 128 * 128];  // 96 KB

  const int tid = threadIdx.x;
  const int lane = tid & 63;
  const int wave = tid >> 6;
  const int g = lane >> 4;    // 0..3
  const int qi = lane & 15;   // 0..15

  // ---- stage all 3 W's (bf16, swizzled: byte ^= ((row&7)<<4)) ----
#pragma unroll
  for (int i = 0; i < 6; ++i) {
    const int byte = (tid + i * 1024) * 16;      // linear byte in [0, 98304)
    const int row = (byte >> 8) & 127;           // row within its matrix
    const int swz = byte ^ ((row & 7) << 4);
    *(bf16x8*)((char*)wlds + swz) = *(const bf16x8*)((const char*)Wb + byte);
  }
  __syncthreads();

  const long row = (long)blockIdx.x * 256 + wave * 16 + qi;  // lane's out row
  const int rswz = (qi & 7) << 4;  // row-swizzle bits for W reads (row=ct*16+qi)

  // X fragment (B operand): lane = col j = its own row; k = kt*32 + g*8 + j
  bf16x8 xk[4];
#pragma unroll
  for (int kt = 0; kt < 4; ++kt)
    xk[kt] = load8_cvt(keys + row * 128 + kt * 32 + g * 8);

  f32x4 acc[8];
  float4 tmp[8];  // nbr+nat, carried from K epilogue to V epilogue

  // ---------------- K projection (W at matrix 1) ----------------
#pragma unroll
  for (int ct = 0; ct < 8; ++ct) {
    acc[ct] = f32x4{0.f, 0.f, 0.f, 0.f};
#pragma unroll
    for (int kt = 0; kt < 4; ++kt) {
      const int byte = 32768 + (ct * 16 + qi) * 256 + ((kt * 64 + g * 16) ^ rswz);
      bf16x8 wf = *(const bf16x8*)((const char*)wlds + byte);
      acc[ct] = mfma32(wf, xk[kt], acc[ct]);
    }
  }
#pragma unroll
  for (int ct = 0; ct < 8; ++ct) {
    const int c0 = ct * 16 + 4 * g;
    const float4 bv = *(const float4*)(Kbias + c0);
    const float4 nb = *(const float4*)(nbr + row * 128 + c0);
    const float4 na = *(const float4*)(nat + row * 128 + c0);
    const float4 p4 = *(const float4*)(pk + row * 128 + c0);
    float4 t;
    t.x = nb.x + na.x; t.y = nb.y + na.y; t.z = nb.z + na.z; t.w = nb.w + na.w;
    tmp[ct] = t;
    ushort4 u;
    u.x = f2b(acc[ct][0] + bv.x + t.x + p4.x);
    u.y = f2b(acc[ct][1] + bv.y + t.y + p4.y);
    u.z = f2b(acc[ct][2] + bv.z + t.z + p4.z);
    u.w = f2b(acc[ct][3] + bv.w + t.w + p4.w);
    *(ushort4*)(Ko + row * 128 + c0) = u;
  }

  // ---------------- V projection (W at matrix 2) ----------------
#pragma unroll
  for (int ct = 0; ct < 8; ++ct) {
    acc[ct] = f32x4{0.f, 0.f, 0.f, 0.f};
#pragma unroll
    for (int kt = 0; kt < 4; ++kt) {
      const int byte = 65536 + (ct * 16 + qi) * 256 + ((kt * 64 + g * 16) ^ rswz);
      bf16x8 wf = *(const bf16x8*)((const char*)wlds + byte);
      acc[ct] = mfma32(wf, xk[kt], acc[ct]);
    }
  }
  {
    const long bidx = row >> 9, lrow = row & 511;
#pragma unroll
    for (int ct = 0; ct < 8; ++ct) {
      const int c0 = ct * 16 + 4 * g;
      const float4 bv = *(const float4*)(Vbias + c0);
      const float4 p4 = *(const float4*)(pv + row * 128 + c0);
      const int hh = c0 >> 6, d0 = c0 & 63;
      unsigned short* vp = Vt + (((long)hh * NB + bidx) * HDIM + d0) * LL + lrow;
      vp[0 * LL] = f2b(acc[ct][0] + bv.x + tmp[ct].x + p4.x);
      vp[1 * LL] = f2b(acc[ct][1] + bv.y + tmp[ct].y + p4.y);
      vp[2 * LL] = f2b(acc[ct][2] + bv.z + tmp[ct].z + p4.z);
      vp[3 * LL] = f2b(acc[ct][3] + bv.w + tmp[ct].w + p4.w);
    }
  }

  // ---------------- Q projection (W at matrix 0) ----------------
  bf16x8 xq[4];
#pragma unroll
  for (int kt = 0; kt < 4; ++kt)
    xq[kt] = load8_cvt(queries + row * 128 + kt * 32 + g * 8);
#pragma unroll
  for (int ct = 0; ct < 8; ++ct) {
    acc[ct] = f32x4{0.f, 0.f, 0.f, 0.f};
#pragma unroll
    for (int kt = 0; kt < 4; ++kt) {
      const int byte = (ct * 16 + qi) * 256 + ((kt * 64 + g * 16) ^ rswz);
      bf16x8 wf = *(const bf16x8*)((const char*)wlds + byte);
      acc[ct] = mfma32(wf, xq[kt], acc[ct]);
    }
  }
#pragma unroll
  for (int ct = 0; ct < 8; ++ct) {
    const int c0 = ct * 16 + 4 * g;
    const float4 bv = *(const float4*)(Qbias + c0);
    ushort4 u;
    u.x = f2b(acc[ct][0] + bv.x);
    u.y = f2b(acc[ct][1] + bv.y);
    u.z = f2b(acc[ct][2] + bv.z);
    u.w = f2b(acc[ct][3] + bv.w);
    *(ushort4*)(Qo + row * 128 + c0) = u;
  }
}

// ---------------------------------------------------------------------------
// Attention kernel (unchanged from R2): K-tile = 64 keys/iter, 32 q/wave,
// swapped QK^T so P lands directly in the 16x16x16 A-fragment layout.
// ---------------------------------------------------------------------------
__global__ __launch_bounds__(256) void attn_kernel(
    const unsigned short* __restrict__ Qb, const unsigned short* __restrict__ Kb,
    const unsigned short* __restrict__ Vt, float* __restrict__ out) {
  const int qt = blockIdx.x;
  const int b = blockIdx.y;
  const int h = blockIdx.z;
  const int tid = threadIdx.x;
  const int lane = tid & 63;
  const int wave = tid >> 6;
  const int g = lane >> 4;
  const int qi = lane & 15;
  const int qbase = qt * 128 + wave * 32;

  bf16x8 qf[2][2];
#pragma unroll
  for (int q2 = 0; q2 < 2; ++q2) {
    const unsigned short* Qrow =
        Qb + ((long)(b * LL + qbase + q2 * 16 + qi)) * HH + h * HDIM;
    qf[q2][0] = *(const bf16x8*)(Qrow + g * 8);
    qf[q2][1] = *(const bf16x8*)(Qrow + 32 + g * 8);
  }

  f32x4 o[2][4];
#pragma unroll
  for (int q2 = 0; q2 < 2; ++q2)
#pragma unroll
    for (int dt = 0; dt < 4; ++dt) o[q2][dt] = f32x4{0.f, 0.f, 0.f, 0.f};
  float m[2] = {-1e30f, -1e30f};
  float lsum[2] = {0.f, 0.f};

  const int ntile = (qbase >> 6) + 1;
  const unsigned short* Vbase = Vt + ((long)(h * NB + b)) * HDIM * LL;

  for (int it = 0; it < ntile; ++it) {
    const int k0 = it * 64;

    bf16x8 kf[4][2];
#pragma unroll
    for (int t = 0; t < 4; ++t) {
      const unsigned short* Krow =
          Kb + ((long)(b * LL + k0 + t * 16 + qi)) * HH + h * HDIM;
      kf[t][0] = *(const bf16x8*)(Krow + g * 8);
      kf[t][1] = *(const bf16x8*)(Krow + 32 + g * 8);
    }

    f32x4 s[2][4];
#pragma unroll
    for (int q2 = 0; q2 < 2; ++q2)
#pragma unroll
      for (int t = 0; t < 4; ++t) {
        f32x4 acc = f32x4{0.f, 0.f, 0.f, 0.f};
        acc = mfma32(kf[t][0], qf[q2][0], acc);
        acc = mfma32(kf[t][1], qf[q2][1], acc);
        s[q2][t] = acc;
      }

    float alpha[2];
    bf16x4 pf[2][4];
#pragma unroll
    for (int q2 = 0; q2 < 2; ++q2) {
      const int myq = qbase + q2 * 16 + qi;
      float p[16];
      float pm = -1e30f;
#pragma unroll
      for (int t = 0; t < 4; ++t)
#pragma unroll
        for (int r = 0; r < 4; ++r) {
          float sv = s[q2][t][r] * 0.125f;
          const int key = k0 + t * 16 + 4 * g + r;
          sv = (key > myq) ? -1e30f : sv;
          p[t * 4 + r] = sv;
          pm = fmaxf(pm, sv);
        }
      pm = fmaxf(pm, __shfl_xor(pm, 16));
      pm = fmaxf(pm, __shfl_xor(pm, 32));
      const float mnew = fmaxf(m[q2], pm);
      alpha[q2] = exp2f((m[q2] - mnew) * 1.44269504f);
      float ps = 0.f;
#pragma unroll
      for (int i = 0; i < 16; ++i) {
        p[i] = exp2f((p[i] - mnew) * 1.44269504f);
        ps += p[i];
      }
      ps += __shfl_xor(ps, 16);
      ps += __shfl_xor(ps, 32);
      lsum[q2] = lsum[q2] * alpha[q2] + ps;
      m[q2] = mnew;
#pragma unroll
      for (int t = 0; t < 4; ++t) {
        pf[q2][t][0] = (short)f2b(p[t * 4 + 0]);
        pf[q2][t][1] = (short)f2b(p[t * 4 + 1]);
        pf[q2][t][2] = (short)f2b(p[t * 4 + 2]);
        pf[q2][t][3] = (short)f2b(p[t * 4 + 3]);
      }
    }

    float ar[2][4];
#pragma unroll
    for (int q2 = 0; q2 < 2; ++q2)
#pragma unroll
      for (int r = 0; r < 4; ++r) ar[q2][r] = __shfl(alpha[q2], 4 * g + r);

#pragma unroll
    for (int dt = 0; dt < 4; ++dt) {
#pragma unroll
      for (int q2 = 0; q2 < 2; ++q2) {
        o[q2][dt][0] *= ar[q2][0];
        o[q2][dt][1] *= ar[q2][1];
        o[q2][dt][2] *= ar[q2][2];
        o[q2][dt][3] *= ar[q2][3];
      }
#pragma unroll
      for (int t = 0; t < 4; ++t) {
        const bf16x4 vf =
            *(const bf16x4*)(Vbase + (dt * 16 + qi) * LL + k0 + t * 16 + 4 * g);
        o[0][dt] = mfma16(pf[0][t], vf, o[0][dt]);
        o[1][dt] = mfma16(pf[1][t], vf, o[1][dt]);
      }
    }
  }

#pragma unroll
  for (int q2 = 0; q2 < 2; ++q2) {
    float linv[4];
#pragma unroll
    for (int r = 0; r < 4; ++r) linv[r] = 1.0f / __shfl(lsum[q2], 4 * g + r);
#pragma unroll
    for (int dt = 0; dt < 4; ++dt)
#pragma unroll
      for (int r = 0; r < 4; ++r) {
        const long row = (long)(b * LL + qbase + q2 * 16 + 4 * g + r);
        out[row * HH + h * HDIM + dt * 16 + qi] = o[q2][dt][r] * linv[r];
      }
  }
}

extern "C" void kernel_launch(void* const* d_in, const int* in_sizes, int n_in,
                              void* d_out, int out_size, void* d_ws, size_t ws_size,
                              hipStream_t stream) {
  const float* queries = (const float*)d_in[0];
  const float* keys    = (const float*)d_in[1];
  const float* nbr     = (const float*)d_in[2];
  const float* nat     = (const float*)d_in[3];
  const float* pk      = (const float*)d_in[4];
  const float* pv      = (const float*)d_in[5];
  const float* Qw      = (const float*)d_in[6];
  const float* Qbias   = (const float*)d_in[7];
  const float* Kw      = (const float*)d_in[8];
  const float* Kbias   = (const float*)d_in[9];
  const float* Vw      = (const float*)d_in[10];
  const float* Vbias   = (const float*)d_in[11];
  // d_in[12] = attn_mask: exact causal ~tril, computed analytically in-kernel.

  unsigned short* Qo = (unsigned short*)d_ws;
  unsigned short* Ko = Qo + (size_t)NROWS * HH;
  unsigned short* Vt = Ko + (size_t)NROWS * HH;
  unsigned short* Wb = Vt + (size_t)NROWS * HH;  // [3][128][128] bf16, linear

  wcvt_kernel<<<48, 256, 0, stream>>>(Qw, Kw, Vw, Wb);

  proj_kernel<<<NROWS / 256, 1024, 0, stream>>>(queries, keys, nbr, nat, pk, pv,
                                                Wb, Qbias, Kbias, Vbias,
                                                Qo, Ko, Vt);

  dim3 grid(LL / 128, NB, 2);
  attn_kernel<<<grid, 256, 0, stream>>>(Qo, Ko, Vt, (float*)d_out);
}

// Round 5
// 153.077 us; speedup vs baseline: 1.3847x; 1.0532x over previous
//
#include <hip/hip_runtime.h>

typedef __attribute__((ext_vector_type(8))) short bf16x8;
typedef __attribute__((ext_vector_type(4))) short bf16x4;
typedef __attribute__((ext_vector_type(4))) float f32x4;

#define NB 128
#define LL 512
#define HH 128
#define HDIM 64
#define NROWS (NB * LL)  // 65536

__device__ __forceinline__ unsigned short f2b(float f) {
  unsigned int x = __float_as_uint(f);
  x = (x + 0x7fffu + ((x >> 16) & 1u)) >> 16;  // RNE
  return (unsigned short)x;
}

__device__ __forceinline__ bf16x8 load8_cvt(const float* p) {
  float4 a = *(const float4*)p;
  float4 b = *(const float4*)(p + 4);
  bf16x8 r;
  r[0] = (short)f2b(a.x); r[1] = (short)f2b(a.y);
  r[2] = (short)f2b(a.z); r[3] = (short)f2b(a.w);
  r[4] = (short)f2b(b.x); r[5] = (short)f2b(b.y);
  r[6] = (short)f2b(b.z); r[7] = (short)f2b(b.w);
  return r;
}

#if __has_builtin(__builtin_amdgcn_mfma_f32_16x16x16bf16_1k)
__device__ __forceinline__ f32x4 mfma16(bf16x4 a, bf16x4 b, f32x4 c) {
  return __builtin_amdgcn_mfma_f32_16x16x16bf16_1k(a, b, c, 0, 0, 0);
}
#else
__device__ __forceinline__ f32x4 mfma16(bf16x4 a, bf16x4 b, f32x4 c) {
  asm volatile("s_nop 1\n\t"
               "v_mfma_f32_16x16x16_bf16 %0, %1, %2, %0\n\t"
               "s_nop 7\n\t"
               "s_nop 7"
               : "+v"(c) : "v"(a), "v"(b));
  return c;
}
#endif

__device__ __forceinline__ f32x4 mfma32(bf16x8 a, bf16x8 b, f32x4 c) {
  return __builtin_amdgcn_mfma_f32_16x16x32_bf16(a, b, c, 0, 0, 0);
}

// ---------------------------------------------------------------------------
// Weight pre-convert: fp32 -> bf16, LINEAR layout Wb[3][128][128] (Q,K,V).
// ---------------------------------------------------------------------------
__global__ __launch_bounds__(256) void wcvt_kernel(
    const float* __restrict__ Qw, const float* __restrict__ Kw,
    const float* __restrict__ Vw, unsigned short* __restrict__ Wb) {
  const int i = blockIdx.x * 256 + threadIdx.x;  // 0..12287 float4s
  const float* src = (i < 4096) ? Qw : (i < 8192) ? Kw : Vw;
  const int off = (i & 4095) << 2;
  float4 v = *(const float4*)(src + off);
  ushort4 u;
  u.x = f2b(v.x); u.y = f2b(v.y); u.z = f2b(v.z); u.w = f2b(v.w);
  *(ushort4*)(Wb + ((size_t)i << 2)) = u;
}

// ---------------------------------------------------------------------------
// KV projection: Kw+Vw staged in 64KB LDS (2 blocks/CU). Software-pipelined:
// epilogue stream loads issued in chunks BEFORE MFMA clusters, consumed after.
//   Ko [65536][128] = keys @ Kw^T + Kb + nbr + nat + pk   (bf16)
//   Vt [2][128][64][512]  = (keys @ Vw^T + Vb + nbr + nat + pv)^T
// Grid: 512 blocks x 512 threads (8 waves x 16 rows).
// ---------------------------------------------------------------------------
__global__ __launch_bounds__(512) void kv_proj_kernel(
    const float* __restrict__ keys, const float* __restrict__ nbr,
    const float* __restrict__ nat, const float* __restrict__ pk,
    const float* __restrict__ pv, const unsigned short* __restrict__ Wb,
    const float* __restrict__ Kbias, const float* __restrict__ Vbias,
    unsigned short* __restrict__ Ko, unsigned short* __restrict__ Vt) {
  __shared__ unsigned short wlds[2 * 128 * 128];  // 64 KB: Kw, Vw (swizzled)

  const int tid = threadIdx.x;
  const int lane = tid & 63;
  const int wave = tid >> 6;
  const int g = lane >> 4;    // 0..3
  const int qi = lane & 15;   // 0..15

  // stage Kw,Vw (bf16, swizzle byte ^= ((row&7)<<4))
#pragma unroll
  for (int i = 0; i < 8; ++i) {
    const int byte = (tid + i * 512) * 16;  // [0, 65536)
    const int row = (byte >> 8) & 127;
    *(bf16x8*)((char*)wlds + (byte ^ ((row & 7) << 4))) =
        *(const bf16x8*)((const char*)Wb + 32768 + byte);
  }

  const long row = (long)blockIdx.x * 128 + wave * 16 + qi;
  const int rswz = (qi & 7) << 4;
  const long roff = row * 128;

  // X fragments (issued before the barrier so they fly during staging wait)
  bf16x8 xk[4];
#pragma unroll
  for (int kt = 0; kt < 4; ++kt)
    xk[kt] = load8_cvt(keys + roff + kt * 32 + g * 8);

  // chunk A: nbr/nat/pk for ct 0..3
  float4 Anb[4], Ana[4], Apk[4];
#pragma unroll
  for (int ct = 0; ct < 4; ++ct) {
    const int c0 = ct * 16 + 4 * g;
    Anb[ct] = *(const float4*)(nbr + roff + c0);
    Ana[ct] = *(const float4*)(nat + roff + c0);
    Apk[ct] = *(const float4*)(pk + roff + c0);
  }

  __syncthreads();

  float4 tmp[8];  // nbr+nat, carried to V epilogue

  // ---- MFMA K ct0..3 ----
  f32x4 accK[8];
#pragma unroll
  for (int ct = 0; ct < 4; ++ct) {
    accK[ct] = f32x4{0.f, 0.f, 0.f, 0.f};
#pragma unroll
    for (int kt = 0; kt < 4; ++kt) {
      const int byte = (ct * 16 + qi) * 256 + ((kt * 64 + g * 16) ^ rswz);
      bf16x8 wf = *(const bf16x8*)((const char*)wlds + byte);
      accK[ct] = mfma32(wf, xk[kt], accK[ct]);
    }
  }

  // ---- consume A -> Ko ct0..3 ----
#pragma unroll
  for (int ct = 0; ct < 4; ++ct) {
    const int c0 = ct * 16 + 4 * g;
    const float4 bv = *(const float4*)(Kbias + c0);
    float4 t;
    t.x = Anb[ct].x + Ana[ct].x; t.y = Anb[ct].y + Ana[ct].y;
    t.z = Anb[ct].z + Ana[ct].z; t.w = Anb[ct].w + Ana[ct].w;
    tmp[ct] = t;
    ushort4 u;
    u.x = f2b(accK[ct][0] + bv.x + t.x + Apk[ct].x);
    u.y = f2b(accK[ct][1] + bv.y + t.y + Apk[ct].y);
    u.z = f2b(accK[ct][2] + bv.z + t.z + Apk[ct].z);
    u.w = f2b(accK[ct][3] + bv.w + t.w + Apk[ct].w);
    *(ushort4*)(Ko + roff + c0) = u;
  }

  // ---- chunk B: nbr/nat/pk ct4..7 ----
  float4 Bnb[4], Bna[4], Bpk[4];
#pragma unroll
  for (int ct = 0; ct < 4; ++ct) {
    const int c0 = (ct + 4) * 16 + 4 * g;
    Bnb[ct] = *(const float4*)(nbr + roff + c0);
    Bna[ct] = *(const float4*)(nat + roff + c0);
    Bpk[ct] = *(const float4*)(pk + roff + c0);
  }

  // ---- MFMA K ct4..7 ----
#pragma unroll
  for (int ct = 4; ct < 8; ++ct) {
    accK[ct] = f32x4{0.f, 0.f, 0.f, 0.f};
#pragma unroll
    for (int kt = 0; kt < 4; ++kt) {
      const int byte = (ct * 16 + qi) * 256 + ((kt * 64 + g * 16) ^ rswz);
      bf16x8 wf = *(const bf16x8*)((const char*)wlds + byte);
      accK[ct] = mfma32(wf, xk[kt], accK[ct]);
    }
  }

  // ---- chunk C: pv ct0..3 ----
  float4 Cpv[4];
#pragma unroll
  for (int ct = 0; ct < 4; ++ct)
    Cpv[ct] = *(const float4*)(pv + roff + ct * 16 + 4 * g);

  // ---- consume B -> Ko ct4..7 ----
#pragma unroll
  for (int ct = 4; ct < 8; ++ct) {
    const int c0 = ct * 16 + 4 * g;
    const float4 bv = *(const float4*)(Kbias + c0);
    const int j = ct - 4;
    float4 t;
    t.x = Bnb[j].x + Bna[j].x; t.y = Bnb[j].y + Bna[j].y;
    t.z = Bnb[j].z + Bna[j].z; t.w = Bnb[j].w + Bna[j].w;
    tmp[ct] = t;
    ushort4 u;
    u.x = f2b(accK[ct][0] + bv.x + t.x + Bpk[j].x);
    u.y = f2b(accK[ct][1] + bv.y + t.y + Bpk[j].y);
    u.z = f2b(accK[ct][2] + bv.z + t.z + Bpk[j].z);
    u.w = f2b(accK[ct][3] + bv.w + t.w + Bpk[j].w);
    *(ushort4*)(Ko + roff + c0) = u;
  }

  const long bidx = row >> 9, lrow = row & 511;

  // ---- MFMA V ct0..3 ----
  f32x4 accV[8];
#pragma unroll
  for (int ct = 0; ct < 4; ++ct) {
    accV[ct] = f32x4{0.f, 0.f, 0.f, 0.f};
#pragma unroll
    for (int kt = 0; kt < 4; ++kt) {
      const int byte = 32768 + (ct * 16 + qi) * 256 + ((kt * 64 + g * 16) ^ rswz);
      bf16x8 wf = *(const bf16x8*)((const char*)wlds + byte);
      accV[ct] = mfma32(wf, xk[kt], accV[ct]);
    }
  }

  // ---- chunk D: pv ct4..7 ----
  float4 Dpv[4];
#pragma unroll
  for (int ct = 0; ct < 4; ++ct)
    Dpv[ct] = *(const float4*)(pv + roff + (ct + 4) * 16 + 4 * g);

  // ---- consume C -> Vt ct0..3 ----
#pragma unroll
  for (int ct = 0; ct < 4; ++ct) {
    const int c0 = ct * 16 + 4 * g;
    const float4 bv = *(const float4*)(Vbias + c0);
    const int hh = c0 >> 6, d0 = c0 & 63;
    unsigned short* vp = Vt + (((long)hh * NB + bidx) * HDIM + d0) * LL + lrow;
    vp[0 * LL] = f2b(accV[ct][0] + bv.x + tmp[ct].x + Cpv[ct].x);
    vp[1 * LL] = f2b(accV[ct][1] + bv.y + tmp[ct].y + Cpv[ct].y);
    vp[2 * LL] = f2b(accV[ct][2] + bv.z + tmp[ct].z + Cpv[ct].z);
    vp[3 * LL] = f2b(accV[ct][3] + bv.w + tmp[ct].w + Cpv[ct].w);
  }

  // ---- MFMA V ct4..7 ----
#pragma unroll
  for (int ct = 4; ct < 8; ++ct) {
    accV[ct] = f32x4{0.f, 0.f, 0.f, 0.f};
#pragma unroll
    for (int kt = 0; kt < 4; ++kt) {
      const int byte = 32768 + (ct * 16 + qi) * 256 + ((kt * 64 + g * 16) ^ rswz);
      bf16x8 wf = *(const bf16x8*)((const char*)wlds + byte);
      accV[ct] = mfma32(wf, xk[kt], accV[ct]);
    }
  }

  // ---- consume D -> Vt ct4..7 ----
#pragma unroll
  for (int ct = 4; ct < 8; ++ct) {
    const int c0 = ct * 16 + 4 * g;
    const float4 bv = *(const float4*)(Vbias + c0);
    const int j = ct - 4;
    const int hh = c0 >> 6, d0 = c0 & 63;
    unsigned short* vp = Vt + (((long)hh * NB + bidx) * HDIM + d0) * LL + lrow;
    vp[0 * LL] = f2b(accV[ct][0] + bv.x + tmp[ct].x + Dpv[j].x);
    vp[1 * LL] = f2b(accV[ct][1] + bv.y + tmp[ct].y + Dpv[j].y);
    vp[2 * LL] = f2b(accV[ct][2] + bv.z + tmp[ct].z + Dpv[j].z);
    vp[3 * LL] = f2b(accV[ct][3] + bv.w + tmp[ct].w + Dpv[j].w);
  }
}

// ---------------------------------------------------------------------------
// Q projection: Qw in 32KB LDS (3 blocks/CU). Light epilogue (bias only).
// Grid: 512 blocks x 512 threads (8 waves x 16 rows).
// ---------------------------------------------------------------------------
__global__ __launch_bounds__(512) void q_proj_kernel(
    const float* __restrict__ queries, const unsigned short* __restrict__ Wb,
    const float* __restrict__ Qbias, unsigned short* __restrict__ Qo) {
  __shared__ unsigned short wlds[128 * 128];  // 32 KB

  const int tid = threadIdx.x;
  const int lane = tid & 63;
  const int wave = tid >> 6;
  const int g = lane >> 4, qi = lane & 15;

#pragma unroll
  for (int i = 0; i < 4; ++i) {
    const int byte = (tid + i * 512) * 16;  // [0, 32768)
    const int row = (byte >> 8) & 127;
    *(bf16x8*)((char*)wlds + (byte ^ ((row & 7) << 4))) =
        *(const bf16x8*)((const char*)Wb + byte);
  }

  const long row = (long)blockIdx.x * 128 + wave * 16 + qi;
  const int rswz = (qi & 7) << 4;
  const long roff = row * 128;

  bf16x8 xq[4];
#pragma unroll
  for (int kt = 0; kt < 4; ++kt)
    xq[kt] = load8_cvt(queries + roff + kt * 32 + g * 8);

  __syncthreads();

  f32x4 acc[8];
#pragma unroll
  for (int ct = 0; ct < 8; ++ct) {
    acc[ct] = f32x4{0.f, 0.f, 0.f, 0.f};
#pragma unroll
    for (int kt = 0; kt < 4; ++kt) {
      const int byte = (ct * 16 + qi) * 256 + ((kt * 64 + g * 16) ^ rswz);
      bf16x8 wf = *(const bf16x8*)((const char*)wlds + byte);
      acc[ct] = mfma32(wf, xq[kt], acc[ct]);
    }
  }
#pragma unroll
  for (int ct = 0; ct < 8; ++ct) {
    const int c0 = ct * 16 + 4 * g;
    const float4 bv = *(const float4*)(Qbias + c0);
    ushort4 u;
    u.x = f2b(acc[ct][0] + bv.x);
    u.y = f2b(acc[ct][1] + bv.y);
    u.z = f2b(acc[ct][2] + bv.z);
    u.w = f2b(acc[ct][3] + bv.w);
    *(ushort4*)(Qo + roff + c0) = u;
  }
}

// ---------------------------------------------------------------------------
// Attention kernel: K-tile = 64 keys/iter, 32 q/wave, swapped QK^T.
// 1-D grid of 1024 with XCD-aware remap: the 4 q-tile blocks of one (b,h)
// land on the SAME XCD so K/V panels hit that XCD's L2.
// ---------------------------------------------------------------------------
__global__ __launch_bounds__(256) void attn_kernel(
    const unsigned short* __restrict__ Qb, const unsigned short* __restrict__ Kb,
    const unsigned short* __restrict__ Vt, float* __restrict__ out) {
  const int id = blockIdx.x;          // 0..1023
  const int xcd = id & 7;             // dispatch round-robins id%8 over XCDs
  const int slot = id >> 3;           // 0..127
  const int qt = slot & 3;
  const int bh = xcd * 32 + (slot >> 2);  // bijective: [0,256)
  const int b = bh & 127;
  const int h = bh >> 7;

  const int tid = threadIdx.x;
  const int lane = tid & 63;
  const int wave = tid >> 6;
  const int g = lane >> 4;
  const int qi = lane & 15;
  const int qbase = qt * 128 + wave * 32;

  bf16x8 qf[2][2];
#pragma unroll
  for (int q2 = 0; q2 < 2; ++q2) {
    const unsigned short* Qrow =
        Qb + ((long)(b * LL + qbase + q2 * 16 + qi)) * HH + h * HDIM;
    qf[q2][0] = *(const bf16x8*)(Qrow + g * 8);
    qf[q2][1] = *(const bf16x8*)(Qrow + 32 + g * 8);
  }

  f32x4 o[2][4];
#pragma unroll
  for (int q2 = 0; q2 < 2; ++q2)
#pragma unroll
    for (int dt = 0; dt < 4; ++dt) o[q2][dt] = f32x4{0.f, 0.f, 0.f, 0.f};
  float m[2] = {-1e30f, -1e30f};
  float lsum[2] = {0.f, 0.f};

  const int ntile = (qbase >> 6) + 1;
  const unsigned short* Vbase = Vt + ((long)(h * NB + b)) * HDIM * LL;

  for (int it = 0; it < ntile; ++it) {
    const int k0 = it * 64;

    bf16x8 kf[4][2];
#pragma unroll
    for (int t = 0; t < 4; ++t) {
      const unsigned short* Krow =
          Kb + ((long)(b * LL + k0 + t * 16 + qi)) * HH + h * HDIM;
      kf[t][0] = *(const bf16x8*)(Krow + g * 8);
      kf[t][1] = *(const bf16x8*)(Krow + 32 + g * 8);
    }

    f32x4 s[2][4];
#pragma unroll
    for (int q2 = 0; q2 < 2; ++q2)
#pragma unroll
      for (int t = 0; t < 4; ++t) {
        f32x4 acc = f32x4{0.f, 0.f, 0.f, 0.f};
        acc = mfma32(kf[t][0], qf[q2][0], acc);
        acc = mfma32(kf[t][1], qf[q2][1], acc);
        s[q2][t] = acc;
      }

    float alpha[2];
    bf16x4 pf[2][4];
#pragma unroll
    for (int q2 = 0; q2 < 2; ++q2) {
      const int myq = qbase + q2 * 16 + qi;
      float p[16];
      float pm = -1e30f;
#pragma unroll
      for (int t = 0; t < 4; ++t)
#pragma unroll
        for (int r = 0; r < 4; ++r) {
          float sv = s[q2][t][r] * 0.125f;
          const int key = k0 + t * 16 + 4 * g + r;
          sv = (key > myq) ? -1e30f : sv;
          p[t * 4 + r] = sv;
          pm = fmaxf(pm, sv);
        }
      pm = fmaxf(pm, __shfl_xor(pm, 16));
      pm = fmaxf(pm, __shfl_xor(pm, 32));
      const float mnew = fmaxf(m[q2], pm);
      alpha[q2] = exp2f((m[q2] - mnew) * 1.44269504f);
      float ps = 0.f;
#pragma unroll
      for (int i = 0; i < 16; ++i) {
        p[i] = exp2f((p[i] - mnew) * 1.44269504f);
        ps += p[i];
      }
      ps += __shfl_xor(ps, 16);
      ps += __shfl_xor(ps, 32);
      lsum[q2] = lsum[q2] * alpha[q2] + ps;
      m[q2] = mnew;
#pragma unroll
      for (int t = 0; t < 4; ++t) {
        pf[q2][t][0] = (short)f2b(p[t * 4 + 0]);
        pf[q2][t][1] = (short)f2b(p[t * 4 + 1]);
        pf[q2][t][2] = (short)f2b(p[t * 4 + 2]);
        pf[q2][t][3] = (short)f2b(p[t * 4 + 3]);
      }
    }

    float ar[2][4];
#pragma unroll
    for (int q2 = 0; q2 < 2; ++q2)
#pragma unroll
      for (int r = 0; r < 4; ++r) ar[q2][r] = __shfl(alpha[q2], 4 * g + r);

#pragma unroll
    for (int dt = 0; dt < 4; ++dt) {
#pragma unroll
      for (int q2 = 0; q2 < 2; ++q2) {
        o[q2][dt][0] *= ar[q2][0];
        o[q2][dt][1] *= ar[q2][1];
        o[q2][dt][2] *= ar[q2][2];
        o[q2][dt][3] *= ar[q2][3];
      }
#pragma unroll
      for (int t = 0; t < 4; ++t) {
        const bf16x4 vf =
            *(const bf16x4*)(Vbase + (dt * 16 + qi) * LL + k0 + t * 16 + 4 * g);
        o[0][dt] = mfma16(pf[0][t], vf, o[0][dt]);
        o[1][dt] = mfma16(pf[1][t], vf, o[1][dt]);
      }
    }
  }

#pragma unroll
  for (int q2 = 0; q2 < 2; ++q2) {
    float linv[4];
#pragma unroll
    for (int r = 0; r < 4; ++r) linv[r] = 1.0f / __shfl(lsum[q2], 4 * g + r);
#pragma unroll
    for (int dt = 0; dt < 4; ++dt)
#pragma unroll
      for (int r = 0; r < 4; ++r) {
        const long row = (long)(b * LL + qbase + q2 * 16 + 4 * g + r);
        out[row * HH + h * HDIM + dt * 16 + qi] = o[q2][dt][r] * linv[r];
      }
  }
}

extern "C" void kernel_launch(void* const* d_in, const int* in_sizes, int n_in,
                              void* d_out, int out_size, void* d_ws, size_t ws_size,
                              hipStream_t stream) {
  const float* queries = (const float*)d_in[0];
  const float* keys    = (const float*)d_in[1];
  const float* nbr     = (const float*)d_in[2];
  const float* nat     = (const float*)d_in[3];
  const float* pk      = (const float*)d_in[4];
  const float* pv      = (const float*)d_in[5];
  const float* Qw      = (const float*)d_in[6];
  const float* Qbias   = (const float*)d_in[7];
  const float* Kw      = (const float*)d_in[8];
  const float* Kbias   = (const float*)d_in[9];
  const float* Vw      = (const float*)d_in[10];
  const float* Vbias   = (const float*)d_in[11];
  // d_in[12] = attn_mask: exact causal ~tril, computed analytically in-kernel.

  unsigned short* Qo = (unsigned short*)d_ws;
  unsigned short* Ko = Qo + (size_t)NROWS * HH;
  unsigned short* Vt = Ko + (size_t)NROWS * HH;
  unsigned short* Wb = Vt + (size_t)NROWS * HH;  // [3][128][128] bf16, linear

  wcvt_kernel<<<48, 256, 0, stream>>>(Qw, Kw, Vw, Wb);

  kv_proj_kernel<<<NROWS / 128, 512, 0, stream>>>(keys, nbr, nat, pk, pv, Wb,
                                                  Kbias, Vbias, Ko, Vt);
  q_proj_kernel<<<NROWS / 128, 512, 0, stream>>>(queries, Wb, Qbias, Qo);

  attn_kernel<<<1024, 256, 0, stream>>>(Qo, Ko, Vt, (float*)d_out);
}

// Round 6
// 125.334 us; speedup vs baseline: 1.6913x; 1.2214x over previous
//
#include <hip/hip_runtime.h>

typedef __attribute__((ext_vector_type(8))) short bf16x8;
typedef __attribute__((ext_vector_type(4))) short bf16x4;
typedef __attribute__((ext_vector_type(4))) float f32x4;

#define NB 128
#define LL 512
#define HH 128
#define HDIM 64
#define NROWS (NB * LL)  // 65536

__device__ __forceinline__ unsigned short f2b(float f) {
  unsigned int x = __float_as_uint(f);
  x = (x + 0x7fffu + ((x >> 16) & 1u)) >> 16;  // RNE
  return (unsigned short)x;
}

__device__ __forceinline__ bf16x8 load8_cvt(const float* p) {
  float4 a = *(const float4*)p;
  float4 b = *(const float4*)(p + 4);
  bf16x8 r;
  r[0] = (short)f2b(a.x); r[1] = (short)f2b(a.y);
  r[2] = (short)f2b(a.z); r[3] = (short)f2b(a.w);
  r[4] = (short)f2b(b.x); r[5] = (short)f2b(b.y);
  r[6] = (short)f2b(b.z); r[7] = (short)f2b(b.w);
  return r;
}

#if __has_builtin(__builtin_amdgcn_mfma_f32_16x16x16bf16_1k)
__device__ __forceinline__ f32x4 mfma16(bf16x4 a, bf16x4 b, f32x4 c) {
  return __builtin_amdgcn_mfma_f32_16x16x16bf16_1k(a, b, c, 0, 0, 0);
}
#else
__device__ __forceinline__ f32x4 mfma16(bf16x4 a, bf16x4 b, f32x4 c) {
  asm volatile("s_nop 1\n\t"
               "v_mfma_f32_16x16x16_bf16 %0, %1, %2, %0\n\t"
               "s_nop 7\n\t"
               "s_nop 7"
               : "+v"(c) : "v"(a), "v"(b));
  return c;
}
#endif

__device__ __forceinline__ f32x4 mfma32(bf16x8 a, bf16x8 b, f32x4 c) {
  return __builtin_amdgcn_mfma_f32_16x16x32_bf16(a, b, c, 0, 0, 0);
}

// ---------------------------------------------------------------------------
// Weight pre-convert: fp32 -> bf16, LINEAR layout Wb[3][128][128] (Q,K,V).
// ---------------------------------------------------------------------------
__global__ __launch_bounds__(256) void wcvt_kernel(
    const float* __restrict__ Qw, const float* __restrict__ Kw,
    const float* __restrict__ Vw, unsigned short* __restrict__ Wb) {
  const int i = blockIdx.x * 256 + threadIdx.x;  // 0..12287 float4s
  const float* src = (i < 4096) ? Qw : (i < 8192) ? Kw : Vw;
  const int off = (i & 4095) << 2;
  float4 v = *(const float4*)(src + off);
  ushort4 u;
  u.x = f2b(v.x); u.y = f2b(v.y); u.z = f2b(v.z); u.w = f2b(v.w);
  *(ushort4*)(Wb + ((size_t)i << 2)) = u;
}

// ---------------------------------------------------------------------------
// KV projection (unchanged from R5): Kw+Vw in 64KB LDS, pipelined epilogue.
// ---------------------------------------------------------------------------
__global__ __launch_bounds__(512) void kv_proj_kernel(
    const float* __restrict__ keys, const float* __restrict__ nbr,
    const float* __restrict__ nat, const float* __restrict__ pk,
    const float* __restrict__ pv, const unsigned short* __restrict__ Wb,
    const float* __restrict__ Kbias, const float* __restrict__ Vbias,
    unsigned short* __restrict__ Ko, unsigned short* __restrict__ Vt) {
  __shared__ unsigned short wlds[2 * 128 * 128];  // 64 KB: Kw, Vw (swizzled)

  const int tid = threadIdx.x;
  const int lane = tid & 63;
  const int wave = tid >> 6;
  const int g = lane >> 4;
  const int qi = lane & 15;

#pragma unroll
  for (int i = 0; i < 8; ++i) {
    const int byte = (tid + i * 512) * 16;
    const int row = (byte >> 8) & 127;
    *(bf16x8*)((char*)wlds + (byte ^ ((row & 7) << 4))) =
        *(const bf16x8*)((const char*)Wb + 32768 + byte);
  }

  const long row = (long)blockIdx.x * 128 + wave * 16 + qi;
  const int rswz = (qi & 7) << 4;
  const long roff = row * 128;

  bf16x8 xk[4];
#pragma unroll
  for (int kt = 0; kt < 4; ++kt)
    xk[kt] = load8_cvt(keys + roff + kt * 32 + g * 8);

  float4 Anb[4], Ana[4], Apk[4];
#pragma unroll
  for (int ct = 0; ct < 4; ++ct) {
    const int c0 = ct * 16 + 4 * g;
    Anb[ct] = *(const float4*)(nbr + roff + c0);
    Ana[ct] = *(const float4*)(nat + roff + c0);
    Apk[ct] = *(const float4*)(pk + roff + c0);
  }

  __syncthreads();

  float4 tmp[8];

  f32x4 accK[8];
#pragma unroll
  for (int ct = 0; ct < 4; ++ct) {
    accK[ct] = f32x4{0.f, 0.f, 0.f, 0.f};
#pragma unroll
    for (int kt = 0; kt < 4; ++kt) {
      const int byte = (ct * 16 + qi) * 256 + ((kt * 64 + g * 16) ^ rswz);
      bf16x8 wf = *(const bf16x8*)((const char*)wlds + byte);
      accK[ct] = mfma32(wf, xk[kt], accK[ct]);
    }
  }

#pragma unroll
  for (int ct = 0; ct < 4; ++ct) {
    const int c0 = ct * 16 + 4 * g;
    const float4 bv = *(const float4*)(Kbias + c0);
    float4 t;
    t.x = Anb[ct].x + Ana[ct].x; t.y = Anb[ct].y + Ana[ct].y;
    t.z = Anb[ct].z + Ana[ct].z; t.w = Anb[ct].w + Ana[ct].w;
    tmp[ct] = t;
    ushort4 u;
    u.x = f2b(accK[ct][0] + bv.x + t.x + Apk[ct].x);
    u.y = f2b(accK[ct][1] + bv.y + t.y + Apk[ct].y);
    u.z = f2b(accK[ct][2] + bv.z + t.z + Apk[ct].z);
    u.w = f2b(accK[ct][3] + bv.w + t.w + Apk[ct].w);
    *(ushort4*)(Ko + roff + c0) = u;
  }

  float4 Bnb[4], Bna[4], Bpk[4];
#pragma unroll
  for (int ct = 0; ct < 4; ++ct) {
    const int c0 = (ct + 4) * 16 + 4 * g;
    Bnb[ct] = *(const float4*)(nbr + roff + c0);
    Bna[ct] = *(const float4*)(nat + roff + c0);
    Bpk[ct] = *(const float4*)(pk + roff + c0);
  }

#pragma unroll
  for (int ct = 4; ct < 8; ++ct) {
    accK[ct] = f32x4{0.f, 0.f, 0.f, 0.f};
#pragma unroll
    for (int kt = 0; kt < 4; ++kt) {
      const int byte = (ct * 16 + qi) * 256 + ((kt * 64 + g * 16) ^ rswz);
      bf16x8 wf = *(const bf16x8*)((const char*)wlds + byte);
      accK[ct] = mfma32(wf, xk[kt], accK[ct]);
    }
  }

  float4 Cpv[4];
#pragma unroll
  for (int ct = 0; ct < 4; ++ct)
    Cpv[ct] = *(const float4*)(pv + roff + ct * 16 + 4 * g);

#pragma unroll
  for (int ct = 4; ct < 8; ++ct) {
    const int c0 = ct * 16 + 4 * g;
    const float4 bv = *(const float4*)(Kbias + c0);
    const int j = ct - 4;
    float4 t;
    t.x = Bnb[j].x + Bna[j].x; t.y = Bnb[j].y + Bna[j].y;
    t.z = Bnb[j].z + Bna[j].z; t.w = Bnb[j].w + Bna[j].w;
    tmp[ct] = t;
    ushort4 u;
    u.x = f2b(accK[ct][0] + bv.x + t.x + Bpk[j].x);
    u.y = f2b(accK[ct][1] + bv.y + t.y + Bpk[j].y);
    u.z = f2b(accK[ct][2] + bv.z + t.z + Bpk[j].z);
    u.w = f2b(accK[ct][3] + bv.w + t.w + Bpk[j].w);
    *(ushort4*)(Ko + roff + c0) = u;
  }

  const long bidx = row >> 9, lrow = row & 511;

  f32x4 accV[8];
#pragma unroll
  for (int ct = 0; ct < 4; ++ct) {
    accV[ct] = f32x4{0.f, 0.f, 0.f, 0.f};
#pragma unroll
    for (int kt = 0; kt < 4; ++kt) {
      const int byte = 32768 + (ct * 16 + qi) * 256 + ((kt * 64 + g * 16) ^ rswz);
      bf16x8 wf = *(const bf16x8*)((const char*)wlds + byte);
      accV[ct] = mfma32(wf, xk[kt], accV[ct]);
    }
  }

  float4 Dpv[4];
#pragma unroll
  for (int ct = 0; ct < 4; ++ct)
    Dpv[ct] = *(const float4*)(pv + roff + (ct + 4) * 16 + 4 * g);

#pragma unroll
  for (int ct = 0; ct < 4; ++ct) {
    const int c0 = ct * 16 + 4 * g;
    const float4 bv = *(const float4*)(Vbias + c0);
    const int hh = c0 >> 6, d0 = c0 & 63;
    unsigned short* vp = Vt + (((long)hh * NB + bidx) * HDIM + d0) * LL + lrow;
    vp[0 * LL] = f2b(accV[ct][0] + bv.x + tmp[ct].x + Cpv[ct].x);
    vp[1 * LL] = f2b(accV[ct][1] + bv.y + tmp[ct].y + Cpv[ct].y);
    vp[2 * LL] = f2b(accV[ct][2] + bv.z + tmp[ct].z + Cpv[ct].z);
    vp[3 * LL] = f2b(accV[ct][3] + bv.w + tmp[ct].w + Cpv[ct].w);
  }

#pragma unroll
  for (int ct = 4; ct < 8; ++ct) {
    accV[ct] = f32x4{0.f, 0.f, 0.f, 0.f};
#pragma unroll
    for (int kt = 0; kt < 4; ++kt) {
      const int byte = 32768 + (ct * 16 + qi) * 256 + ((kt * 64 + g * 16) ^ rswz);
      bf16x8 wf = *(const bf16x8*)((const char*)wlds + byte);
      accV[ct] = mfma32(wf, xk[kt], accV[ct]);
    }
  }

#pragma unroll
  for (int ct = 4; ct < 8; ++ct) {
    const int c0 = ct * 16 + 4 * g;
    const float4 bv = *(const float4*)(Vbias + c0);
    const int j = ct - 4;
    const int hh = c0 >> 6, d0 = c0 & 63;
    unsigned short* vp = Vt + (((long)hh * NB + bidx) * HDIM + d0) * LL + lrow;
    vp[0 * LL] = f2b(accV[ct][0] + bv.x + tmp[ct].x + Dpv[j].x);
    vp[1 * LL] = f2b(accV[ct][1] + bv.y + tmp[ct].y + Dpv[j].y);
    vp[2 * LL] = f2b(accV[ct][2] + bv.z + tmp[ct].z + Dpv[j].z);
    vp[3 * LL] = f2b(accV[ct][3] + bv.w + tmp[ct].w + Dpv[j].w);
  }
}

// ---------------------------------------------------------------------------
// Q projection (unchanged from R5): Qw in 32KB LDS.
// ---------------------------------------------------------------------------
__global__ __launch_bounds__(512) void q_proj_kernel(
    const float* __restrict__ queries, const unsigned short* __restrict__ Wb,
    const float* __restrict__ Qbias, unsigned short* __restrict__ Qo) {
  __shared__ unsigned short wlds[128 * 128];  // 32 KB

  const int tid = threadIdx.x;
  const int lane = tid & 63;
  const int wave = tid >> 6;
  const int g = lane >> 4, qi = lane & 15;

#pragma unroll
  for (int i = 0; i < 4; ++i) {
    const int byte = (tid + i * 512) * 16;
    const int row = (byte >> 8) & 127;
    *(bf16x8*)((char*)wlds + (byte ^ ((row & 7) << 4))) =
        *(const bf16x8*)((const char*)Wb + byte);
  }

  const long row = (long)blockIdx.x * 128 + wave * 16 + qi;
  const int rswz = (qi & 7) << 4;
  const long roff = row * 128;

  bf16x8 xq[4];
#pragma unroll
  for (int kt = 0; kt < 4; ++kt)
    xq[kt] = load8_cvt(queries + roff + kt * 32 + g * 8);

  __syncthreads();

  f32x4 acc[8];
#pragma unroll
  for (int ct = 0; ct < 8; ++ct) {
    acc[ct] = f32x4{0.f, 0.f, 0.f, 0.f};
#pragma unroll
    for (int kt = 0; kt < 4; ++kt) {
      const int byte = (ct * 16 + qi) * 256 + ((kt * 64 + g * 16) ^ rswz);
      bf16x8 wf = *(const bf16x8*)((const char*)wlds + byte);
      acc[ct] = mfma32(wf, xq[kt], acc[ct]);
    }
  }
#pragma unroll
  for (int ct = 0; ct < 8; ++ct) {
    const int c0 = ct * 16 + 4 * g;
    const float4 bv = *(const float4*)(Qbias + c0);
    ushort4 u;
    u.x = f2b(acc[ct][0] + bv.x);
    u.y = f2b(acc[ct][1] + bv.y);
    u.z = f2b(acc[ct][2] + bv.z);
    u.w = f2b(acc[ct][3] + bv.w);
    *(ushort4*)(Qo + roff + c0) = u;
  }
}

// ---------------------------------------------------------------------------
// Attention kernel v3: 1-wave blocks (64 thr), LPT dispatch (longest chunk
// first), K double-buffer prefetch, V loads hoisted above softmax.
// Grid: 4096 blocks. id -> chunk c = 15 - (id>>8) (32 q-rows each),
// bh = id & 255. Blocks of the same (b,h) differ by 256 ≡ 0 mod 8 -> same XCD.
// ---------------------------------------------------------------------------
__global__ __launch_bounds__(64) void attn_kernel(
    const unsigned short* __restrict__ Qb, const unsigned short* __restrict__ Kb,
    const unsigned short* __restrict__ Vt, float* __restrict__ out) {
  const int id = blockIdx.x;        // 0..4095
  const int c = 15 - (id >> 8);     // chunk (longest first for LPT)
  const int bh = id & 255;
  const int b = bh & 127;
  const int h = bh >> 7;

  const int lane = threadIdx.x;     // 0..63
  const int g = lane >> 4;
  const int qi = lane & 15;
  const int qbase = c * 32;

  // Q fragments (B operand of swapped QK^T): col q = l&15, k = d
  bf16x8 qf[2][2];
#pragma unroll
  for (int q2 = 0; q2 < 2; ++q2) {
    const unsigned short* Qrow =
        Qb + ((long)(b * LL + qbase + q2 * 16 + qi)) * HH + h * HDIM;
    qf[q2][0] = *(const bf16x8*)(Qrow + g * 8);
    qf[q2][1] = *(const bf16x8*)(Qrow + 32 + g * 8);
  }

  f32x4 o[2][4];
#pragma unroll
  for (int q2 = 0; q2 < 2; ++q2)
#pragma unroll
    for (int dt = 0; dt < 4; ++dt) o[q2][dt] = f32x4{0.f, 0.f, 0.f, 0.f};
  float m[2] = {-1e30f, -1e30f};
  float lsum[2] = {0.f, 0.f};

  const int ntile = (c >> 1) + 1;   // causal
  const unsigned short* Kbb = Kb + (long)b * LL * HH + h * HDIM;
  const unsigned short* Vbase = Vt + ((long)(h * NB + b)) * HDIM * LL;

  // K prefetch: tile 0
  bf16x8 kcur[4][2];
#pragma unroll
  for (int t = 0; t < 4; ++t) {
    const unsigned short* Krow = Kbb + (long)(t * 16 + qi) * HH;
    kcur[t][0] = *(const bf16x8*)(Krow + g * 8);
    kcur[t][1] = *(const bf16x8*)(Krow + 32 + g * 8);
  }

  for (int it = 0; it < ntile; ++it) {
    const int k0 = it * 64;

    // prefetch next K tile (hides under this iteration's compute)
    bf16x8 knxt[4][2];
    if (it + 1 < ntile) {
#pragma unroll
      for (int t = 0; t < 4; ++t) {
        const unsigned short* Krow = Kbb + (long)(k0 + 64 + t * 16 + qi) * HH;
        knxt[t][0] = *(const bf16x8*)(Krow + g * 8);
        knxt[t][1] = *(const bf16x8*)(Krow + 32 + g * 8);
      }
    }

    // V loads for current tile, hoisted above softmax VALU section
    bf16x4 vf[4][4];
#pragma unroll
    for (int dt = 0; dt < 4; ++dt)
#pragma unroll
      for (int t = 0; t < 4; ++t)
        vf[dt][t] =
            *(const bf16x4*)(Vbase + (dt * 16 + qi) * LL + k0 + t * 16 + 4 * g);

    // S' = (K+...)Q^T : lane holds q = l&15 (col), key rows t*16 + 4g + reg
    f32x4 s[2][4];
#pragma unroll
    for (int q2 = 0; q2 < 2; ++q2)
#pragma unroll
      for (int t = 0; t < 4; ++t) {
        f32x4 acc = f32x4{0.f, 0.f, 0.f, 0.f};
        acc = mfma32(kcur[t][0], qf[q2][0], acc);
        acc = mfma32(kcur[t][1], qf[q2][1], acc);
        s[q2][t] = acc;
      }

    float alpha[2];
    bf16x4 pf[2][4];
#pragma unroll
    for (int q2 = 0; q2 < 2; ++q2) {
      const int myq = qbase + q2 * 16 + qi;
      float p[16];
      float pm = -1e30f;
#pragma unroll
      for (int t = 0; t < 4; ++t)
#pragma unroll
        for (int r = 0; r < 4; ++r) {
          float sv = s[q2][t][r] * 0.125f;      // 1/sqrt(64)
          const int key = k0 + t * 16 + 4 * g + r;
          sv = (key > myq) ? -1e30f : sv;       // causal mask
          p[t * 4 + r] = sv;
          pm = fmaxf(pm, sv);
        }
      pm = fmaxf(pm, __shfl_xor(pm, 16));
      pm = fmaxf(pm, __shfl_xor(pm, 32));
      const float mnew = fmaxf(m[q2], pm);
      alpha[q2] = exp2f((m[q2] - mnew) * 1.44269504f);
      float ps = 0.f;
#pragma unroll
      for (int i = 0; i < 16; ++i) {
        p[i] = exp2f((p[i] - mnew) * 1.44269504f);
        ps += p[i];
      }
      ps += __shfl_xor(ps, 16);
      ps += __shfl_xor(ps, 32);
      lsum[q2] = lsum[q2] * alpha[q2] + ps;
      m[q2] = mnew;
#pragma unroll
      for (int t = 0; t < 4; ++t) {
        pf[q2][t][0] = (short)f2b(p[t * 4 + 0]);
        pf[q2][t][1] = (short)f2b(p[t * 4 + 1]);
        pf[q2][t][2] = (short)f2b(p[t * 4 + 2]);
        pf[q2][t][3] = (short)f2b(p[t * 4 + 3]);
      }
    }

    // O-rescale factors transposed to O-row layout (rows q = 4g+reg)
    float ar[2][4];
#pragma unroll
    for (int q2 = 0; q2 < 2; ++q2)
#pragma unroll
      for (int r = 0; r < 4; ++r) ar[q2][r] = __shfl(alpha[q2], 4 * g + r);

#pragma unroll
    for (int dt = 0; dt < 4; ++dt) {
#pragma unroll
      for (int q2 = 0; q2 < 2; ++q2) {
        o[q2][dt][0] *= ar[q2][0];
        o[q2][dt][1] *= ar[q2][1];
        o[q2][dt][2] *= ar[q2][2];
        o[q2][dt][3] *= ar[q2][3];
      }
#pragma unroll
      for (int t = 0; t < 4; ++t) {
        o[0][dt] = mfma16(pf[0][t], vf[dt][t], o[0][dt]);
        o[1][dt] = mfma16(pf[1][t], vf[dt][t], o[1][dt]);
      }
    }

    // rotate K buffers
#pragma unroll
    for (int t = 0; t < 4; ++t) {
      kcur[t][0] = knxt[t][0];
      kcur[t][1] = knxt[t][1];
    }
  }

  // epilogue: divide by row sums (transposed to O-row layout)
#pragma unroll
  for (int q2 = 0; q2 < 2; ++q2) {
    float linv[4];
#pragma unroll
    for (int r = 0; r < 4; ++r) linv[r] = 1.0f / __shfl(lsum[q2], 4 * g + r);
#pragma unroll
    for (int dt = 0; dt < 4; ++dt)
#pragma unroll
      for (int r = 0; r < 4; ++r) {
        const long row = (long)(b * LL + qbase + q2 * 16 + 4 * g + r);
        out[row * HH + h * HDIM + dt * 16 + qi] = o[q2][dt][r] * linv[r];
      }
  }
}

extern "C" void kernel_launch(void* const* d_in, const int* in_sizes, int n_in,
                              void* d_out, int out_size, void* d_ws, size_t ws_size,
                              hipStream_t stream) {
  const float* queries = (const float*)d_in[0];
  const float* keys    = (const float*)d_in[1];
  const float* nbr     = (const float*)d_in[2];
  const float* nat     = (const float*)d_in[3];
  const float* pk      = (const float*)d_in[4];
  const float* pv      = (const float*)d_in[5];
  const float* Qw      = (const float*)d_in[6];
  const float* Qbias   = (const float*)d_in[7];
  const float* Kw      = (const float*)d_in[8];
  const float* Kbias   = (const float*)d_in[9];
  const float* Vw      = (const float*)d_in[10];
  const float* Vbias   = (const float*)d_in[11];
  // d_in[12] = attn_mask: exact causal ~tril, computed analytically in-kernel.

  unsigned short* Qo = (unsigned short*)d_ws;
  unsigned short* Ko = Qo + (size_t)NROWS * HH;
  unsigned short* Vt = Ko + (size_t)NROWS * HH;
  unsigned short* Wb = Vt + (size_t)NROWS * HH;  // [3][128][128] bf16, linear

  wcvt_kernel<<<48, 256, 0, stream>>>(Qw, Kw, Vw, Wb);

  kv_proj_kernel<<<NROWS / 128, 512, 0, stream>>>(keys, nbr, nat, pk, pv, Wb,
                                                  Kbias, Vbias, Ko, Vt);
  q_proj_kernel<<<NROWS / 128, 512, 0, stream>>>(queries, Wb, Qbias, Qo);

  attn_kernel<<<4096, 64, 0, stream>>>(Qo, Ko, Vt, (float*)d_out);
}

// Round 7
// 117.002 us; speedup vs baseline: 1.8117x; 1.0712x over previous
//
#include <hip/hip_runtime.h>

typedef __attribute__((ext_vector_type(8))) short bf16x8;
typedef __attribute__((ext_vector_type(4))) short bf16x4;
typedef __attribute__((ext_vector_type(4))) float f32x4;

#define NB 128
#define LL 512
#define HH 128
#define HDIM 64
#define NROWS (NB * LL)  // 65536

#define SB __builtin_amdgcn_sched_barrier(0)

__device__ __forceinline__ unsigned short f2b(float f) {
  unsigned int x = __float_as_uint(f);
  x = (x + 0x7fffu + ((x >> 16) & 1u)) >> 16;  // RNE
  return (unsigned short)x;
}

__device__ __forceinline__ bf16x8 load8_cvt(const float* p) {
  float4 a = *(const float4*)p;
  float4 b = *(const float4*)(p + 4);
  bf16x8 r;
  r[0] = (short)f2b(a.x); r[1] = (short)f2b(a.y);
  r[2] = (short)f2b(a.z); r[3] = (short)f2b(a.w);
  r[4] = (short)f2b(b.x); r[5] = (short)f2b(b.y);
  r[6] = (short)f2b(b.z); r[7] = (short)f2b(b.w);
  return r;
}

#if __has_builtin(__builtin_amdgcn_mfma_f32_16x16x16bf16_1k)
__device__ __forceinline__ f32x4 mfma16(bf16x4 a, bf16x4 b, f32x4 c) {
  return __builtin_amdgcn_mfma_f32_16x16x16bf16_1k(a, b, c, 0, 0, 0);
}
#else
__device__ __forceinline__ f32x4 mfma16(bf16x4 a, bf16x4 b, f32x4 c) {
  asm volatile("s_nop 1\n\t"
               "v_mfma_f32_16x16x16_bf16 %0, %1, %2, %0\n\t"
               "s_nop 7\n\t"
               "s_nop 7"
               : "+v"(c) : "v"(a), "v"(b));
  return c;
}
#endif

__device__ __forceinline__ f32x4 mfma32(bf16x8 a, bf16x8 b, f32x4 c) {
  return __builtin_amdgcn_mfma_f32_16x16x32_bf16(a, b, c, 0, 0, 0);
}

// ---------------------------------------------------------------------------
// Weight pre-convert: fp32 -> bf16, LINEAR layout Wb[3][128][128] (Q,K,V).
// ---------------------------------------------------------------------------
__global__ __launch_bounds__(256) void wcvt_kernel(
    const float* __restrict__ Qw, const float* __restrict__ Kw,
    const float* __restrict__ Vw, unsigned short* __restrict__ Wb) {
  const int i = blockIdx.x * 256 + threadIdx.x;  // 0..12287 float4s
  const float* src = (i < 4096) ? Qw : (i < 8192) ? Kw : Vw;
  const int off = (i & 4095) << 2;
  float4 v = *(const float4*)(src + off);
  ushort4 u;
  u.x = f2b(v.x); u.y = f2b(v.y); u.z = f2b(v.z); u.w = f2b(v.w);
  *(ushort4*)(Wb + ((size_t)i << 2)) = u;
}

// ---------------------------------------------------------------------------
// KV projection v3: sched_barrier-pinned software pipeline. Loads issued in
// chunks 2-3 sections before their consumers; compiler cannot sink them.
// Sections: {issue loads} SB {MFMA pair (LDS)} SB {epilogue consuming an
// earlier chunk} SB ...
// ---------------------------------------------------------------------------
__global__ __launch_bounds__(512, 4) void kv_proj_kernel(
    const float* __restrict__ keys, const float* __restrict__ nbr,
    const float* __restrict__ nat, const float* __restrict__ pk,
    const float* __restrict__ pv, const unsigned short* __restrict__ Wb,
    const float* __restrict__ Kbias, const float* __restrict__ Vbias,
    unsigned short* __restrict__ Ko, unsigned short* __restrict__ Vt) {
  __shared__ unsigned short wlds[2 * 128 * 128];  // 64 KB: Kw, Vw (swizzled)

  const int tid = threadIdx.x;
  const int lane = tid & 63;
  const int wave = tid >> 6;
  const int g = lane >> 4;
  const int qi = lane & 15;

  // ---- stage Kw,Vw into LDS (swizzle byte ^= ((row&7)<<4)) ----
#pragma unroll
  for (int i = 0; i < 8; ++i) {
    const int byte = (tid + i * 512) * 16;
    const int row = (byte >> 8) & 127;
    *(bf16x8*)((char*)wlds + (byte ^ ((row & 7) << 4))) =
        *(const bf16x8*)((const char*)Wb + 32768 + byte);
  }

  const long row = (long)blockIdx.x * 128 + wave * 16 + qi;
  const int rswz = (qi & 7) << 4;
  const long roff = row * 128;

  float4 Anb[8], Ana[8], Apk[8], Apv[8];
  float4 tmp[8];
  f32x4 accK[8], accV[8];

  // ---- S0: issue xk + chunk {ct0,ct1} ----
  float4 xr[8];
#pragma unroll
  for (int j = 0; j < 8; ++j)
    xr[j] = *(const float4*)(keys + roff + (j >> 1) * 32 + g * 8 + (j & 1) * 4);
#pragma unroll
  for (int ct = 0; ct < 2; ++ct) {
    const int c0 = ct * 16 + 4 * g;
    Anb[ct] = *(const float4*)(nbr + roff + c0);
    Ana[ct] = *(const float4*)(nat + roff + c0);
    Apk[ct] = *(const float4*)(pk + roff + c0);
  }
  SB;
  bf16x8 xk[4];
#pragma unroll
  for (int kt = 0; kt < 4; ++kt) {
    const float4 a = xr[2 * kt], b = xr[2 * kt + 1];
    bf16x8 r;
    r[0] = (short)f2b(a.x); r[1] = (short)f2b(a.y);
    r[2] = (short)f2b(a.z); r[3] = (short)f2b(a.w);
    r[4] = (short)f2b(b.x); r[5] = (short)f2b(b.y);
    r[6] = (short)f2b(b.z); r[7] = (short)f2b(b.w);
    xk[kt] = r;
  }
  __syncthreads();

  // ---- S1: issue chunks {ct2,3} {ct4,5} ----
#pragma unroll
  for (int ct = 2; ct < 6; ++ct) {
    const int c0 = ct * 16 + 4 * g;
    Anb[ct] = *(const float4*)(nbr + roff + c0);
    Ana[ct] = *(const float4*)(nat + roff + c0);
    Apk[ct] = *(const float4*)(pk + roff + c0);
  }
  SB;

#define MFMA_K_PAIR(c)                                                      \
  {                                                                         \
    _Pragma("unroll") for (int ct = (c); ct < (c) + 2; ++ct) {              \
      accK[ct] = f32x4{0.f, 0.f, 0.f, 0.f};                                 \
      _Pragma("unroll") for (int kt = 0; kt < 4; ++kt) {                    \
        const int byte = (ct * 16 + qi) * 256 + ((kt * 64 + g * 16) ^ rswz);\
        bf16x8 wf = *(const bf16x8*)((const char*)wlds + byte);             \
        accK[ct] = mfma32(wf, xk[kt], accK[ct]);                            \
      }                                                                     \
    }                                                                       \
  }

#define MFMA_V_PAIR(c)                                                      \
  {                                                                         \
    _Pragma("unroll") for (int ct = (c); ct < (c) + 2; ++ct) {              \
      accV[ct] = f32x4{0.f, 0.f, 0.f, 0.f};                                 \
      _Pragma("unroll") for (int kt = 0; kt < 4; ++kt) {                    \
        const int byte =                                                    \
            32768 + (ct * 16 + qi) * 256 + ((kt * 64 + g * 16) ^ rswz);     \
        bf16x8 wf = *(const bf16x8*)((const char*)wlds + byte);             \
        accV[ct] = mfma32(wf, xk[kt], accV[ct]);                            \
      }                                                                     \
    }                                                                       \
  }

#define EPI_K_PAIR(c)                                                       \
  {                                                                         \
    _Pragma("unroll") for (int ct = (c); ct < (c) + 2; ++ct) {              \
      const int c0 = ct * 16 + 4 * g;                                       \
      const float4 bv = *(const float4*)(Kbias + c0);                       \
      float4 t;                                                             \
      t.x = Anb[ct].x + Ana[ct].x; t.y = Anb[ct].y + Ana[ct].y;             \
      t.z = Anb[ct].z + Ana[ct].z; t.w = Anb[ct].w + Ana[ct].w;             \
      tmp[ct] = t;                                                          \
      ushort4 u;                                                            \
      u.x = f2b(accK[ct][0] + bv.x + t.x + Apk[ct].x);                      \
      u.y = f2b(accK[ct][1] + bv.y + t.y + Apk[ct].y);                      \
      u.z = f2b(accK[ct][2] + bv.z + t.z + Apk[ct].z);                      \
      u.w = f2b(accK[ct][3] + bv.w + t.w + Apk[ct].w);                      \
      *(ushort4*)(Ko + roff + c0) = u;                                      \
    }                                                                       \
  }

#define EPI_V_PAIR(c)                                                       \
  {                                                                         \
    _Pragma("unroll") for (int ct = (c); ct < (c) + 2; ++ct) {              \
      const int c0 = ct * 16 + 4 * g;                                       \
      const float4 bv = *(const float4*)(Vbias + c0);                       \
      const int hh = c0 >> 6, d0 = c0 & 63;                                 \
      unsigned short* vp =                                                  \
          Vt + (((long)hh * NB + bidx) * HDIM + d0) * LL + lrow;            \
      vp[0 * LL] = f2b(accV[ct][0] + bv.x + tmp[ct].x + Apv[ct].x);         \
      vp[1 * LL] = f2b(accV[ct][1] + bv.y + tmp[ct].y + Apv[ct].y);         \
      vp[2 * LL] = f2b(accV[ct][2] + bv.z + tmp[ct].z + Apv[ct].z);         \
      vp[3 * LL] = f2b(accV[ct][3] + bv.w + tmp[ct].w + Apv[ct].w);         \
    }                                                                       \
  }

#define ISSUE_A_PAIR(c)                                                     \
  {                                                                         \
    _Pragma("unroll") for (int ct = (c); ct < (c) + 2; ++ct) {              \
      const int c0 = ct * 16 + 4 * g;                                       \
      Anb[ct] = *(const float4*)(nbr + roff + c0);                          \
      Ana[ct] = *(const float4*)(nat + roff + c0);                          \
      Apk[ct] = *(const float4*)(pk + roff + c0);                           \
    }                                                                       \
  }

#define ISSUE_PV_PAIR(c)                                                    \
  {                                                                         \
    _Pragma("unroll") for (int ct = (c); ct < (c) + 2; ++ct) {              \
      Apv[ct] = *(const float4*)(pv + roff + ct * 16 + 4 * g);              \
    }                                                                       \
  }

  const long bidx = row >> 9, lrow = row & 511;

  // ---- pinned pipeline ----
  MFMA_K_PAIR(0); SB;
  EPI_K_PAIR(0); SB;         // consume A{0,1} (landed at barrier)
  ISSUE_A_PAIR(6); SB;       // chunk {ct6,7}
  MFMA_K_PAIR(2); SB;
  EPI_K_PAIR(2); SB;         // consume A{2,3} (issued S1)
  ISSUE_PV_PAIR(0); SB;
  MFMA_K_PAIR(4); SB;
  EPI_K_PAIR(4); SB;         // consume A{4,5} (issued S1)
  ISSUE_PV_PAIR(2); SB;
  MFMA_K_PAIR(6); SB;
  EPI_K_PAIR(6); SB;         // consume A{6,7}
  ISSUE_PV_PAIR(4); SB;
  MFMA_V_PAIR(0); SB;
  EPI_V_PAIR(0); SB;         // consume pv{0,1}
  ISSUE_PV_PAIR(6); SB;
  MFMA_V_PAIR(2); SB;
  EPI_V_PAIR(2); SB;
  MFMA_V_PAIR(4); SB;
  EPI_V_PAIR(4); SB;
  MFMA_V_PAIR(6); SB;
  EPI_V_PAIR(6);
}

// ---------------------------------------------------------------------------
// Q projection (unchanged): Qw in 32KB LDS.
// ---------------------------------------------------------------------------
__global__ __launch_bounds__(512) void q_proj_kernel(
    const float* __restrict__ queries, const unsigned short* __restrict__ Wb,
    const float* __restrict__ Qbias, unsigned short* __restrict__ Qo) {
  __shared__ unsigned short wlds[128 * 128];  // 32 KB

  const int tid = threadIdx.x;
  const int lane = tid & 63;
  const int wave = tid >> 6;
  const int g = lane >> 4, qi = lane & 15;

#pragma unroll
  for (int i = 0; i < 4; ++i) {
    const int byte = (tid + i * 512) * 16;
    const int row = (byte >> 8) & 127;
    *(bf16x8*)((char*)wlds + (byte ^ ((row & 7) << 4))) =
        *(const bf16x8*)((const char*)Wb + byte);
  }

  const long row = (long)blockIdx.x * 128 + wave * 16 + qi;
  const int rswz = (qi & 7) << 4;
  const long roff = row * 128;

  bf16x8 xq[4];
#pragma unroll
  for (int kt = 0; kt < 4; ++kt)
    xq[kt] = load8_cvt(queries + roff + kt * 32 + g * 8);

  __syncthreads();

  f32x4 acc[8];
#pragma unroll
  for (int ct = 0; ct < 8; ++ct) {
    acc[ct] = f32x4{0.f, 0.f, 0.f, 0.f};
#pragma unroll
    for (int kt = 0; kt < 4; ++kt) {
      const int byte = (ct * 16 + qi) * 256 + ((kt * 64 + g * 16) ^ rswz);
      bf16x8 wf = *(const bf16x8*)((const char*)wlds + byte);
      acc[ct] = mfma32(wf, xq[kt], acc[ct]);
    }
  }
#pragma unroll
  for (int ct = 0; ct < 8; ++ct) {
    const int c0 = ct * 16 + 4 * g;
    const float4 bv = *(const float4*)(Qbias + c0);
    ushort4 u;
    u.x = f2b(acc[ct][0] + bv.x);
    u.y = f2b(acc[ct][1] + bv.y);
    u.z = f2b(acc[ct][2] + bv.z);
    u.w = f2b(acc[ct][3] + bv.w);
    *(ushort4*)(Qo + roff + c0) = u;
  }
}

// ---------------------------------------------------------------------------
// Attention kernel (unchanged from R6): 1-wave blocks, LPT dispatch,
// K double-buffer, V hoisted, swapped QK^T.
// ---------------------------------------------------------------------------
__global__ __launch_bounds__(64) void attn_kernel(
    const unsigned short* __restrict__ Qb, const unsigned short* __restrict__ Kb,
    const unsigned short* __restrict__ Vt, float* __restrict__ out) {
  const int id = blockIdx.x;        // 0..4095
  const int c = 15 - (id >> 8);     // chunk (longest first for LPT)
  const int bh = id & 255;
  const int b = bh & 127;
  const int h = bh >> 7;

  const int lane = threadIdx.x;     // 0..63
  const int g = lane >> 4;
  const int qi = lane & 15;
  const int qbase = c * 32;

  bf16x8 qf[2][2];
#pragma unroll
  for (int q2 = 0; q2 < 2; ++q2) {
    const unsigned short* Qrow =
        Qb + ((long)(b * LL + qbase + q2 * 16 + qi)) * HH + h * HDIM;
    qf[q2][0] = *(const bf16x8*)(Qrow + g * 8);
    qf[q2][1] = *(const bf16x8*)(Qrow + 32 + g * 8);
  }

  f32x4 o[2][4];
#pragma unroll
  for (int q2 = 0; q2 < 2; ++q2)
#pragma unroll
    for (int dt = 0; dt < 4; ++dt) o[q2][dt] = f32x4{0.f, 0.f, 0.f, 0.f};
  float m[2] = {-1e30f, -1e30f};
  float lsum[2] = {0.f, 0.f};

  const int ntile = (c >> 1) + 1;   // causal
  const unsigned short* Kbb = Kb + (long)b * LL * HH + h * HDIM;
  const unsigned short* Vbase = Vt + ((long)(h * NB + b)) * HDIM * LL;

  bf16x8 kcur[4][2];
#pragma unroll
  for (int t = 0; t < 4; ++t) {
    const unsigned short* Krow = Kbb + (long)(t * 16 + qi) * HH;
    kcur[t][0] = *(const bf16x8*)(Krow + g * 8);
    kcur[t][1] = *(const bf16x8*)(Krow + 32 + g * 8);
  }

  for (int it = 0; it < ntile; ++it) {
    const int k0 = it * 64;

    bf16x8 knxt[4][2];
    if (it + 1 < ntile) {
#pragma unroll
      for (int t = 0; t < 4; ++t) {
        const unsigned short* Krow = Kbb + (long)(k0 + 64 + t * 16 + qi) * HH;
        knxt[t][0] = *(const bf16x8*)(Krow + g * 8);
        knxt[t][1] = *(const bf16x8*)(Krow + 32 + g * 8);
      }
    }

    bf16x4 vf[4][4];
#pragma unroll
    for (int dt = 0; dt < 4; ++dt)
#pragma unroll
      for (int t = 0; t < 4; ++t)
        vf[dt][t] =
            *(const bf16x4*)(Vbase + (dt * 16 + qi) * LL + k0 + t * 16 + 4 * g);

    f32x4 s[2][4];
#pragma unroll
    for (int q2 = 0; q2 < 2; ++q2)
#pragma unroll
      for (int t = 0; t < 4; ++t) {
        f32x4 acc = f32x4{0.f, 0.f, 0.f, 0.f};
        acc = mfma32(kcur[t][0], qf[q2][0], acc);
        acc = mfma32(kcur[t][1], qf[q2][1], acc);
        s[q2][t] = acc;
      }

    float alpha[2];
    bf16x4 pf[2][4];
#pragma unroll
    for (int q2 = 0; q2 < 2; ++q2) {
      const int myq = qbase + q2 * 16 + qi;
      float p[16];
      float pm = -1e30f;
#pragma unroll
      for (int t = 0; t < 4; ++t)
#pragma unroll
        for (int r = 0; r < 4; ++r) {
          float sv = s[q2][t][r] * 0.125f;      // 1/sqrt(64)
          const int key = k0 + t * 16 + 4 * g + r;
          sv = (key > myq) ? -1e30f : sv;       // causal mask
          p[t * 4 + r] = sv;
          pm = fmaxf(pm, sv);
        }
      pm = fmaxf(pm, __shfl_xor(pm, 16));
      pm = fmaxf(pm, __shfl_xor(pm, 32));
      const float mnew = fmaxf(m[q2], pm);
      alpha[q2] = exp2f((m[q2] - mnew) * 1.44269504f);
      float ps = 0.f;
#pragma unroll
      for (int i = 0; i < 16; ++i) {
        p[i] = exp2f((p[i] - mnew) * 1.44269504f);
        ps += p[i];
      }
      ps += __shfl_xor(ps, 16);
      ps += __shfl_xor(ps, 32);
      lsum[q2] = lsum[q2] * alpha[q2] + ps;
      m[q2] = mnew;
#pragma unroll
      for (int t = 0; t < 4; ++t) {
        pf[q2][t][0] = (short)f2b(p[t * 4 + 0]);
        pf[q2][t][1] = (short)f2b(p[t * 4 + 1]);
        pf[q2][t][2] = (short)f2b(p[t * 4 + 2]);
        pf[q2][t][3] = (short)f2b(p[t * 4 + 3]);
      }
    }

    float ar[2][4];
#pragma unroll
    for (int q2 = 0; q2 < 2; ++q2)
#pragma unroll
      for (int r = 0; r < 4; ++r) ar[q2][r] = __shfl(alpha[q2], 4 * g + r);

#pragma unroll
    for (int dt = 0; dt < 4; ++dt) {
#pragma unroll
      for (int q2 = 0; q2 < 2; ++q2) {
        o[q2][dt][0] *= ar[q2][0];
        o[q2][dt][1] *= ar[q2][1];
        o[q2][dt][2] *= ar[q2][2];
        o[q2][dt][3] *= ar[q2][3];
      }
#pragma unroll
      for (int t = 0; t < 4; ++t) {
        o[0][dt] = mfma16(pf[0][t], vf[dt][t], o[0][dt]);
        o[1][dt] = mfma16(pf[1][t], vf[dt][t], o[1][dt]);
      }
    }

#pragma unroll
    for (int t = 0; t < 4; ++t) {
      kcur[t][0] = knxt[t][0];
      kcur[t][1] = knxt[t][1];
    }
  }

#pragma unroll
  for (int q2 = 0; q2 < 2; ++q2) {
    float linv[4];
#pragma unroll
    for (int r = 0; r < 4; ++r) linv[r] = 1.0f / __shfl(lsum[q2], 4 * g + r);
#pragma unroll
    for (int dt = 0; dt < 4; ++dt)
#pragma unroll
      for (int r = 0; r < 4; ++r) {
        const long row = (long)(b * LL + qbase + q2 * 16 + 4 * g + r);
        out[row * HH + h * HDIM + dt * 16 + qi] = o[q2][dt][r] * linv[r];
      }
  }
}

extern "C" void kernel_launch(void* const* d_in, const int* in_sizes, int n_in,
                              void* d_out, int out_size, void* d_ws, size_t ws_size,
                              hipStream_t stream) {
  const float* queries = (const float*)d_in[0];
  const float* keys    = (const float*)d_in[1];
  const float* nbr     = (const float*)d_in[2];
  const float* nat     = (const float*)d_in[3];
  const float* pk      = (const float*)d_in[4];
  const float* pv      = (const float*)d_in[5];
  const float* Qw      = (const float*)d_in[6];
  const float* Qbias   = (const float*)d_in[7];
  const float* Kw      = (const float*)d_in[8];
  const float* Kbias   = (const float*)d_in[9];
  const float* Vw      = (const float*)d_in[10];
  const float* Vbias   = (const float*)d_in[11];
  // d_in[12] = attn_mask: exact causal ~tril, computed analytically in-kernel.

  unsigned short* Qo = (unsigned short*)d_ws;
  unsigned short* Ko = Qo + (size_t)NROWS * HH;
  unsigned short* Vt = Ko + (size_t)NROWS * HH;
  unsigned short* Wb = Vt + (size_t)NROWS * HH;  // [3][128][128] bf16, linear

  wcvt_kernel<<<48, 256, 0, stream>>>(Qw, Kw, Vw, Wb);

  kv_proj_kernel<<<NROWS / 128, 512, 0, stream>>>(keys, nbr, nat, pk, pv, Wb,
                                                  Kbias, Vbias, Ko, Vt);
  q_proj_kernel<<<NROWS / 128, 512, 0, stream>>>(queries, Wb, Qbias, Qo);

  attn_kernel<<<4096, 64, 0, stream>>>(Qo, Ko, Vt, (float*)d_out);
}